// Round 16
// baseline (550.160 us; speedup 1.0000x reference)
//
#include <hip/hip_runtime.h>
#include <hip/hip_bf16.h>

// DiT block: B=8, S=1024, D=1152, H=16, HD=72, HID=4608
// k_gemm8p: 256x256, 8 waves, 4-phase m201-ordered schedule (reads BEFORE the
//   barrier, 2 barriers/phase): {12 deduped ds_read; stage; bar; lgkm0; 16
//   MFMA32; vmcnt(N); bar}. BK=64, LDS 128KB, XOR swizzle, counted vmcnt.
//   qkv (EPI3), fc1 (EPI2), fc2 split-K x3 (EPI5, klen=1536).
// k_gemm: 128^2 4-wave depth-3 counted (r11) for wo (EPI1).
// Attention: swapped QK^T, pre-transposed V, in-lane softmax.

typedef unsigned short u16;
typedef unsigned int u32;
typedef __attribute__((ext_vector_type(8))) short bf16x8;
typedef __attribute__((ext_vector_type(4))) float f32x4;
typedef __attribute__((ext_vector_type(16))) float f32x16;

#define MFMA16(a, b, c) __builtin_amdgcn_mfma_f32_16x16x32_bf16((a), (b), (c), 0, 0, 0)
#define MFMA32(a, b, c) __builtin_amdgcn_mfma_f32_32x32x16_bf16((a), (b), (c), 0, 0, 0)

__device__ __forceinline__ u16 f2bf(float f) {
  __hip_bfloat16 h = __float2bfloat16(f);
  return __builtin_bit_cast(u16, h);
}

__device__ __forceinline__ float bf2f(u16 u) {
  u32 v = ((u32)u) << 16;
  return __builtin_bit_cast(float, v);
}

__device__ __forceinline__ void gload16(const u16* g, u16* l) {
  __builtin_amdgcn_global_load_lds(
      (const __attribute__((address_space(1))) unsigned int*)(const void*)g,
      (__attribute__((address_space(3))) unsigned int*)(void*)l, 16, 0, 0);
}

// ------- mod projection, split-K stage 1 (silu fused) -------
__global__ __launch_bounds__(256) void k_modproj1(const float* __restrict__ cc,
                                                  const float* __restrict__ aw,
                                                  float* __restrict__ partial) {
  __shared__ float lc[8][144];
  int kc = blockIdx.y;
  for (int i = threadIdx.x; i < 1152; i += 256) {
    int b = i / 144, k = i % 144;
    float v = cc[b * 1152 + kc * 144 + k];
    lc[b][k] = v / (1.f + __expf(-v));
  }
  __syncthreads();
  int j = blockIdx.x * 256 + threadIdx.x;
  float acc[8] = {0, 0, 0, 0, 0, 0, 0, 0};
  for (int k = 0; k < 144; ++k) {
    float w = aw[(size_t)(kc * 144 + k) * 6912 + j];
    #pragma unroll
    for (int b = 0; b < 8; ++b) acc[b] += lc[b][k] * w;
  }
  #pragma unroll
  for (int b = 0; b < 8; ++b) partial[((size_t)kc * 8 + b) * 6912 + j] = acc[b];
}

// ------- mod projection stage 2 -------
__global__ __launch_bounds__(256) void k_modproj2(const float* __restrict__ partial,
                                                  const float* __restrict__ ab,
                                                  float* __restrict__ mo) {
  int j = blockIdx.x * 256 + threadIdx.x;
  float bias = ab[j];
  #pragma unroll
  for (int b = 0; b < 8; ++b) {
    float s = 0.f;
    #pragma unroll
    for (int kc = 0; kc < 8; ++kc) s += partial[((size_t)kc * 8 + b) * 6912 + j];
    mo[(size_t)b * 6912 + j] = s + bias;
  }
}

// ------- transpose-convert: in[K][N] f32 -> out[N][K] bf16 -------
__global__ __launch_bounds__(256) void k_tcvt(const float* __restrict__ in, u16* __restrict__ out,
                                              int K, int N) {
  __shared__ float t[32][33];
  int tx = threadIdx.x & 31, ty = threadIdx.x >> 5;
  size_t bx = (size_t)blockIdx.x * 32, by = (size_t)blockIdx.y * 32;
  #pragma unroll
  for (int i = 0; i < 4; ++i) t[ty + 8 * i][tx] = in[(by + ty + 8 * i) * N + bx + tx];
  __syncthreads();
  #pragma unroll
  for (int i = 0; i < 4; ++i) out[(bx + ty + 8 * i) * K + by + tx] = f2bf(t[tx][ty + 8 * i]);
}

// ------- fused LayerNorm + modulate -> bf16 row -------
__global__ __launch_bounds__(256) void k_lnmod(const float* __restrict__ xin,
                                               const float* __restrict__ w,
                                               const float* __restrict__ bs,
                                               const float* __restrict__ mo,
                                               int sh_off, int sc_off, u16* __restrict__ o) {
  int row = blockIdx.x;
  int b = row >> 10;
  int tid = threadIdx.x;
  const float4* x4 = (const float4*)(xin + (size_t)row * 1152);
  float4 v0 = x4[tid];
  float4 v1 = make_float4(0.f, 0.f, 0.f, 0.f);
  if (tid < 32) v1 = x4[256 + tid];
  float s = v0.x + v0.y + v0.z + v0.w + v1.x + v1.y + v1.z + v1.w;
  float sq = v0.x * v0.x + v0.y * v0.y + v0.z * v0.z + v0.w * v0.w +
             v1.x * v1.x + v1.y * v1.y + v1.z * v1.z + v1.w * v1.w;
  #pragma unroll
  for (int d = 32; d > 0; d >>= 1) { s += __shfl_down(s, d); sq += __shfl_down(sq, d); }
  __shared__ float ps[4], pq[4];
  int wid = tid >> 6, lane = tid & 63;
  if (lane == 0) { ps[wid] = s; pq[wid] = sq; }
  __syncthreads();
  float S = ps[0] + ps[1] + ps[2] + ps[3];
  float SQ = pq[0] + pq[1] + pq[2] + pq[3];
  float mean = S * (1.f / 1152.f);
  float var = SQ * (1.f / 1152.f) - mean * mean;
  float rs = rsqrtf(var + 1e-5f);
  const float* shp = mo + (size_t)b * 6912 + sh_off;
  const float* scp = mo + (size_t)b * 6912 + sc_off;
  u16* orow = o + (size_t)row * 1152;
  {
    int col = 4 * tid;
    ushort4 u; float y;
    y = (v0.x - mean) * rs * w[col + 0] + bs[col + 0]; u.x = f2bf(y * (1.f + scp[col + 0]) + shp[col + 0]);
    y = (v0.y - mean) * rs * w[col + 1] + bs[col + 1]; u.y = f2bf(y * (1.f + scp[col + 1]) + shp[col + 1]);
    y = (v0.z - mean) * rs * w[col + 2] + bs[col + 2]; u.z = f2bf(y * (1.f + scp[col + 2]) + shp[col + 2]);
    y = (v0.w - mean) * rs * w[col + 3] + bs[col + 3]; u.w = f2bf(y * (1.f + scp[col + 3]) + shp[col + 3]);
    *(ushort4*)&orow[col] = u;
  }
  if (tid < 32) {
    int col = 1024 + 4 * tid;
    ushort4 u; float y;
    y = (v1.x - mean) * rs * w[col + 0] + bs[col + 0]; u.x = f2bf(y * (1.f + scp[col + 0]) + shp[col + 0]);
    y = (v1.y - mean) * rs * w[col + 1] + bs[col + 1]; u.y = f2bf(y * (1.f + scp[col + 1]) + shp[col + 1]);
    y = (v1.z - mean) * rs * w[col + 2] + bs[col + 2]; u.z = f2bf(y * (1.f + scp[col + 2]) + shp[col + 2]);
    y = (v1.w - mean) * rs * w[col + 3] + bs[col + 3]; u.w = f2bf(y * (1.f + scp[col + 3]) + shp[col + 3]);
    *(ushort4*)&orow[col] = u;
  }
}

// ======= 4-PHASE GEMM (m201 phase order): BM=BN=256, 512 thr, BK=64 =======
// klen must be a multiple of 128. Phase = {reads; stage; bar; lgkm0; MFMA; VM; bar}.
// EPI 2: gelu, stride gridDim.x*256 (fc1)
// EPI 3: QKV (Q,K stride 3456; V transposed to vt)
// EPI 5: bf16 partial, stride 1152, guard gcol<1152, z-offset (fc2 split-K)
template <int EPI>
__global__ __launch_bounds__(512, 2) void k_gemm8p(const u16* __restrict__ A,
                                                   const u16* __restrict__ Bt,
                                                   int Kst, int klen,
                                                   u16* __restrict__ Cb,
                                                   const float* __restrict__ bias,
                                                   u16* __restrict__ vt) {
  const int tid = threadIdx.x;
  const int w = tid >> 6, lane = tid & 63;
  const int wm = w >> 2, wn = w & 3;
  const int l31 = lane & 31, hi = lane >> 5;

  const int nwg = gridDim.x * gridDim.y;
  const int id = blockIdx.y * gridDim.x + blockIdx.x;
  const int swz = (id & 7) * (nwg >> 3) + (id >> 3);
  const int tM = (swz / gridDim.x) * 256, tN = (swz % gridDim.x) * 256;
  const int koff = blockIdx.z * klen;

  __shared__ u16 lA[2][2][256 * 32];
  __shared__ u16 lB[2][2][256 * 32];
  f32x16 acc[4][2];
  #pragma unroll
  for (int m = 0; m < 4; ++m)
    #pragma unroll
    for (int n = 0; n < 2; ++n)
      #pragma unroll
      for (int r = 0; r < 16; ++r) acc[m][n][r] = 0.f;

  const int lrow = lane >> 2, lseg = lane & 3;
  const int fl = (lrow & 3) ^ ((lrow >> 2) & 3);
  const u16* gA = A + (size_t)(tM + w * 32 + lrow) * Kst + (lseg ^ fl) * 8 + koff;
  const u16* gB = Bt + (size_t)(tN + w * 32 + lrow) * Kst + (lseg ^ fl) * 8 + koff;
  const size_t rstep = (size_t)16 * Kst;
  const int wo0 = (w * 32) * 32, wo1 = (w * 32 + 16) * 32;
  const int fr = (l31 & 3) ^ ((l31 >> 2) & 3);
  const int c0 = (hi ^ fr) * 8;
  const int c1 = ((hi ^ fr) ^ 2) * 8;
  const int arow = (wm * 128 + l31) * 32;
  const int brow = (wn * 64 + l31) * 32;

#define SA(BUF, KH, KO)                                       \
  do {                                                        \
    gload16(gA + (KO), &lA[BUF][KH][wo0]);                    \
    gload16(gA + rstep + (KO), &lA[BUF][KH][wo1]);            \
  } while (0)
#define SB(BUF, KH, KO)                                       \
  do {                                                        \
    gload16(gB + (KO), &lB[BUF][KH][wo0]);                    \
    gload16(gB + rstep + (KO), &lB[BUF][KH][wo1]);            \
  } while (0)
#define VM(Nst) asm volatile("s_waitcnt vmcnt(" #Nst ")" ::: "memory")

// m201-ordered phase: reads of slot (CB,KH) BEFORE the barrier (latency hidden
// by barrier-arrival skew); stage next slot; bar; lgkm0; MFMA; VM_STMT; bar.
// Safety: bar#2 (after all waves' lgkm0) separates reads of a slot from its
// re-stage; VM before bar#2 guarantees next phase's slot resident for all waves.
#define PHASE(CB, KH, STAGE_STMT, VM_STMT)                                      \
  do {                                                                          \
    bf16x8 af[4][2], bf[2][2];                                                  \
    _Pragma("unroll")                                                           \
    for (int m_ = 0; m_ < 4; ++m_) {                                            \
      af[m_][0] = *(const bf16x8*)&lA[CB][KH][arow + m_ * 1024 + c0];           \
      af[m_][1] = *(const bf16x8*)&lA[CB][KH][arow + m_ * 1024 + c1];           \
    }                                                                           \
    _Pragma("unroll")                                                           \
    for (int n_ = 0; n_ < 2; ++n_) {                                            \
      bf[n_][0] = *(const bf16x8*)&lB[CB][KH][brow + n_ * 1024 + c0];           \
      bf[n_][1] = *(const bf16x8*)&lB[CB][KH][brow + n_ * 1024 + c1];           \
    }                                                                           \
    STAGE_STMT;                                                                 \
    __builtin_amdgcn_s_barrier();                                               \
    asm volatile("s_waitcnt lgkmcnt(0)" ::: "memory");                          \
    __builtin_amdgcn_sched_barrier(0);                                          \
    __builtin_amdgcn_s_setprio(1);                                              \
    _Pragma("unroll")                                                           \
    for (int m_ = 0; m_ < 4; ++m_)                                              \
      _Pragma("unroll")                                                         \
      for (int n_ = 0; n_ < 2; ++n_)                                            \
        acc[m_][n_] = MFMA32(af[m_][0], bf[n_][0], acc[m_][n_]);                \
    _Pragma("unroll")                                                           \
    for (int m_ = 0; m_ < 4; ++m_)                                              \
      _Pragma("unroll")                                                         \
      for (int n_ = 0; n_ < 2; ++n_)                                            \
        acc[m_][n_] = MFMA32(af[m_][1], bf[n_][1], acc[m_][n_]);                \
    __builtin_amdgcn_s_setprio(0);                                              \
    VM_STMT;                                                                    \
    __builtin_amdgcn_s_barrier();                                               \
    __builtin_amdgcn_sched_barrier(0);                                          \
  } while (0)

  const int NIT = klen >> 7;
  // prologue: 3 slots (12 gloads); drain slot0; align
  SA(0, 0, 0); SB(0, 0, 0);
  SA(0, 1, 32); SB(0, 1, 32);
  SA(1, 0, 64); SB(1, 0, 64);
  VM(8);
  __builtin_amdgcn_s_barrier();
  __builtin_amdgcn_sched_barrier(0);
  for (int it = 0; it < NIT - 1; ++it) {
    const int kb = it * 128;
    PHASE(0, 0, { SA(1, 1, kb + 96);  SB(1, 1, kb + 96);  }, VM(8));
    PHASE(0, 1, { SA(0, 0, kb + 128); SB(0, 0, kb + 128); }, VM(8));
    PHASE(1, 0, { SA(0, 1, kb + 160); SB(0, 1, kb + 160); }, VM(8));
    PHASE(1, 1, { SA(1, 0, kb + 192); SB(1, 0, kb + 192); }, VM(8));
  }
  {  // tail: stage only final slot; drain 8 -> 4 -> 0
    const int kb = (NIT - 1) * 128;
    PHASE(0, 0, { SA(1, 1, kb + 96); SB(1, 1, kb + 96); }, VM(8));
    PHASE(0, 1, (void)0, VM(4));
    PHASE(1, 0, (void)0, VM(0));
    PHASE(1, 1, (void)0, (void)0);
  }
#undef SA
#undef SB
#undef VM
#undef PHASE

  // epilogue: 32x32 D layout: col = lane&31, row = (reg&3) + 8*(reg>>2) + 4*(lane>>5)
  #pragma unroll
  for (int m = 0; m < 4; ++m)
    #pragma unroll
    for (int n = 0; n < 2; ++n) {
      int gcol = tN + wn * 64 + n * 32 + l31;
      #pragma unroll
      for (int q = 0; q < 4; ++q) {
        int grow0 = tM + wm * 128 + m * 32 + hi * 4 + q * 8;
        if (EPI == 3) {
          if (gcol < 2304) {
            #pragma unroll
            for (int r = 0; r < 4; ++r)
              Cb[(size_t)(grow0 + r) * 3456 + gcol] = f2bf(acc[m][n][q * 4 + r]);
          } else if (gcol < 3456) {
            int qq = gcol - 2304;
            int hh = qq / 72;
            int d = qq - hh * 72;
            int bb = grow0 >> 10, sl = grow0 & 1023;
            ushort4 u;
            u.x = f2bf(acc[m][n][q * 4 + 0]); u.y = f2bf(acc[m][n][q * 4 + 1]);
            u.z = f2bf(acc[m][n][q * 4 + 2]); u.w = f2bf(acc[m][n][q * 4 + 3]);
            *(ushort4*)&vt[(((size_t)bb * 16 + hh) * 72 + d) * 1024 + sl] = u;
          }
        } else if (EPI == 5) {
          if (gcol < 1152) {
            u16* Po = Cb + (size_t)blockIdx.z * 9437184ull;  // 8192*1152
            #pragma unroll
            for (int r = 0; r < 4; ++r)
              Po[(size_t)(grow0 + r) * 1152 + gcol] = f2bf(acc[m][n][q * 4 + r]);
          }
        } else {  // EPI 2: fast gelu
          const int NC = gridDim.x * 256;
          float bi = bias[gcol];
          #pragma unroll
          for (int r = 0; r < 4; ++r) {
            float z = acc[m][n][q * 4 + r] + bi;
            float z2 = z * z;
            float u = z * __fmaf_rn(z2, -0.0713548162f, -1.5957691216f);
            float e = __expf(u);
            Cb[(size_t)(grow0 + r) * NC + gcol] = f2bf(z * __builtin_amdgcn_rcpf(1.f + e));
          }
        }
      }
    }
}

// ------- 128x128 4-wave GEMM (r11, for wo): 32x32 frags, depth-3 counted-vmcnt -------
template <int EPI>
__global__ __launch_bounds__(256) void k_gemm(const u16* __restrict__ A, const u16* __restrict__ Bt,
                                              int Kst, int klen, u16* __restrict__ Cb,
                                              float* __restrict__ Cf,
                                              const float* __restrict__ bias,
                                              const float* __restrict__ res,
                                              const float* __restrict__ mo, int goff,
                                              u16* __restrict__ vt) {
  const int tid = threadIdx.x;
  const int w = tid >> 6, lane = tid & 63;
  const int wr = w >> 1, wc = w & 1;
  const int l31 = lane & 31, hi = lane >> 5;

  const int nwg = gridDim.x * gridDim.y;
  const int id = blockIdx.y * gridDim.x + blockIdx.x;
  const int swz = (id & 7) * (nwg >> 3) + (id >> 3);
  const int tM = (swz / gridDim.x) * 128, tN = (swz % gridDim.x) * 128;
  const int N = gridDim.x * 128;
  const int koff = blockIdx.z * klen;

  __shared__ u16 lA[3][128 * 32];
  __shared__ u16 lB[3][128 * 32];
  f32x16 acc[2][2];
  #pragma unroll
  for (int m = 0; m < 2; ++m)
    #pragma unroll
    for (int n = 0; n < 2; ++n)
      #pragma unroll
      for (int r = 0; r < 16; ++r) acc[m][n][r] = 0.f;

  const int lrow = lane >> 2, lseg = lane & 3;
  const int fl = (lrow & 3) ^ ((lrow >> 2) & 3);
  const u16* gA = A + (size_t)(tM + w * 32 + lrow) * Kst + (lseg ^ fl) * 8 + koff;
  const u16* gB = Bt + (size_t)(tN + w * 32 + lrow) * Kst + (lseg ^ fl) * 8 + koff;
  const size_t rstep = (size_t)16 * Kst;
  const int wo0 = (w * 32) * 32, wo1 = (w * 32 + 16) * 32;
  const int fr = (l31 & 3) ^ ((l31 >> 2) & 3);
  const int c0 = (hi ^ fr) * 8;
  const int c1 = ((hi ^ fr) ^ 2) * 8;
  const int arow = (wr * 64 + l31) * 32;
  const int brow = (wc * 64 + l31) * 32;

#define STAGE(buf, ks)                        \
  do {                                        \
    gload16(gA + (ks), lA[buf] + wo0);        \
    gload16(gA + rstep + (ks), lA[buf] + wo1);\
    gload16(gB + (ks), lB[buf] + wo0);        \
    gload16(gB + rstep + (ks), lB[buf] + wo1);\
  } while (0)

#define COMPUTE(buf)                                                            \
  do {                                                                          \
    bf16x8 a00 = *(const bf16x8*)&lA[buf][arow + c0];                           \
    bf16x8 a01 = *(const bf16x8*)&lA[buf][arow + c1];                           \
    bf16x8 a10 = *(const bf16x8*)&lA[buf][arow + 1024 + c0];                    \
    bf16x8 a11 = *(const bf16x8*)&lA[buf][arow + 1024 + c1];                    \
    bf16x8 b00 = *(const bf16x8*)&lB[buf][brow + c0];                           \
    bf16x8 b01 = *(const bf16x8*)&lB[buf][brow + c1];                           \
    bf16x8 b10 = *(const bf16x8*)&lB[buf][brow + 1024 + c0];                    \
    bf16x8 b11 = *(const bf16x8*)&lB[buf][brow + 1024 + c1];                    \
    __builtin_amdgcn_s_setprio(1);                                              \
    acc[0][0] = MFMA32(a00, b00, acc[0][0]);                                    \
    acc[0][1] = MFMA32(a00, b10, acc[0][1]);                                    \
    acc[1][0] = MFMA32(a10, b00, acc[1][0]);                                    \
    acc[1][1] = MFMA32(a10, b10, acc[1][1]);                                    \
    acc[0][0] = MFMA32(a01, b01, acc[0][0]);                                    \
    acc[0][1] = MFMA32(a01, b11, acc[0][1]);                                    \
    acc[1][0] = MFMA32(a11, b01, acc[1][0]);                                    \
    acc[1][1] = MFMA32(a11, b11, acc[1][1]);                                    \
    __builtin_amdgcn_s_setprio(0);                                              \
  } while (0)

#define WAITBAR(Nst)                                          \
  do {                                                        \
    asm volatile("s_waitcnt vmcnt(" #Nst ")" ::: "memory");   \
    __builtin_amdgcn_s_barrier();                             \
    __builtin_amdgcn_sched_barrier(0);                        \
  } while (0)

  const int nt = klen >> 5;
  STAGE(0, 0);
  STAGE(1, 32);
  int ks = 64;
  for (int g = 0; g < nt / 3 - 1; ++g) {
    WAITBAR(4); STAGE(2, ks);      COMPUTE(0);
    WAITBAR(4); STAGE(0, ks + 32); COMPUTE(1);
    WAITBAR(4); STAGE(1, ks + 64); COMPUTE(2);
    ks += 96;
  }
  WAITBAR(4); STAGE(2, ks); COMPUTE(0);
  WAITBAR(4); COMPUTE(1);
  WAITBAR(0); COMPUTE(2);
#undef STAGE
#undef COMPUTE
#undef WAITBAR

  #pragma unroll
  for (int m = 0; m < 2; ++m)
    #pragma unroll
    for (int n = 0; n < 2; ++n) {
      int gcol = tN + wc * 64 + n * 32 + l31;
      #pragma unroll
      for (int q = 0; q < 4; ++q) {
        int grow0 = tM + wr * 64 + m * 32 + hi * 4 + q * 8;
        float g = mo[(size_t)(grow0 >> 10) * 6912 + goff + gcol];
        float bi = bias[gcol];
        #pragma unroll
        for (int r = 0; r < 4; ++r) {
          size_t idx = (size_t)(grow0 + r) * N + gcol;
          Cf[idx] = res[idx] + g * (acc[m][n][q * 4 + r] + bi);
        }
      }
    }
}

// ------- fc2 split-K x3 reduce: out = x1 + g_mlp*(p0+p1+p2+bias); stride 1152 -------
__global__ __launch_bounds__(256) void k_fc2red(const u16* __restrict__ p,
                                                const float* __restrict__ x1,
                                                const float* __restrict__ bias,
                                                const float* __restrict__ mo,
                                                float* __restrict__ out) {
  size_t i = ((size_t)blockIdx.x * 256 + threadIdx.x) * 4;
  int row = (int)(i / 1152);
  int col = (int)(i - (size_t)row * 1152);
  int b = row >> 10;
  ushort4 a0 = *(const ushort4*)(p + i);
  ushort4 a1 = *(const ushort4*)(p + 9437184ull + i);
  ushort4 a2 = *(const ushort4*)(p + 18874368ull + i);
  float4 r = *(const float4*)(x1 + i);
  const float* gp = mo + (size_t)b * 6912 + 5760 + col;
  const float* bp = bias + col;
  float4 o;
  o.x = r.x + gp[0] * (bf2f(a0.x) + bf2f(a1.x) + bf2f(a2.x) + bp[0]);
  o.y = r.y + gp[1] * (bf2f(a0.y) + bf2f(a1.y) + bf2f(a2.y) + bp[1]);
  o.z = r.z + gp[2] * (bf2f(a0.z) + bf2f(a1.z) + bf2f(a2.z) + bp[2]);
  o.w = r.w + gp[3] * (bf2f(a0.w) + bf2f(a1.w) + bf2f(a2.w) + bp[3]);
  *(float4*)(out + i) = o;
}

// ------- flash attention, swapped-QK^T structure -------
__global__ __launch_bounds__(256) void k_attn(const u16* __restrict__ QKV, const u16* __restrict__ Vt,
                                              u16* __restrict__ O) {
  const int tid = threadIdx.x;
  const int w = tid >> 6, lane = tid & 63;
  const int lr = lane & 15, kg = lane >> 4;
  int bx = blockIdx.x;
  bx = (bx & 7) * 256 + (bx >> 3);
  const int qt = bx & 15, h = (bx >> 4) & 15, b = bx >> 8;

  __shared__ u16 lQ[64][104];
  __shared__ u16 lK[64][104];
  __shared__ u16 lVt[80][72];
  __shared__ u16 lPt[4][16][72];

  const size_t qkbase = (size_t)b * 1024 * 3456 + (size_t)h * 72;
  const u16* Qg = QKV + qkbase;
  const u16* Kg = QKV + qkbase + 1152;
  const u16* Vg = Vt + ((size_t)(b * 16 + h) * 72) * 1024;

  const uint4 z4 = make_uint4(0, 0, 0, 0);
  for (int L = tid; L < 192; L += 256) {
    int r = L / 3, s = L - (L / 3) * 3;
    *(uint4*)&lQ[r][72 + s * 8] = z4;
    *(uint4*)&lK[r][72 + s * 8] = z4;
  }
  for (int L = tid; L < 72; L += 256) {
    int r = L / 9, s = L - (L / 9) * 9;
    *(uint4*)&lVt[72 + r][s * 8] = z4;
  }
  {
    int L = tid; int r = L / 9, s = L - r * 9;
    *(uint4*)&lQ[r][s * 8] = *(const uint4*)(Qg + (size_t)(qt * 64 + r) * 3456 + s * 8);
    L = tid + 256; r = L / 9; s = L - r * 9;
    *(uint4*)&lQ[r][s * 8] = *(const uint4*)(Qg + (size_t)(qt * 64 + r) * 3456 + s * 8);
    if (tid < 64) {
      L = tid + 512; r = L / 9; s = L - r * 9;
      *(uint4*)&lQ[r][s * 8] = *(const uint4*)(Qg + (size_t)(qt * 64 + r) * 3456 + s * 8);
    }
  }
  __syncthreads();

  bf16x8 bq[3];
  #pragma unroll
  for (int ks = 0; ks < 3; ++ks) bq[ks] = *(const bf16x8*)&lQ[w * 16 + lr][ks * 32 + kg * 8];

  const float scale = 0.11785113019775793f;  // 1/sqrt(72)
  float mrun = -1e30f, lrun = 0.f;
  f32x4 oacc[5];
  #pragma unroll
  for (int nd = 0; nd < 5; ++nd) oacc[nd] = f32x4{0.f, 0.f, 0.f, 0.f};

  for (int kt = 0; kt < 16; ++kt) {
    __syncthreads();
    {
      int L = tid; int r = L / 9, s = L - (L / 9) * 9;
      *(uint4*)&lK[r][s * 8] = *(const uint4*)(Kg + (size_t)(kt * 64 + r) * 3456 + s * 8);
      int d = tid >> 3, sg = tid & 7;
      *(uint4*)&lVt[d][sg * 8] = *(const uint4*)(Vg + (size_t)d * 1024 + kt * 64 + sg * 8);
      L = tid + 256; r = L / 9; s = L - r * 9;
      *(uint4*)&lK[r][s * 8] = *(const uint4*)(Kg + (size_t)(kt * 64 + r) * 3456 + s * 8);
      d = (tid + 256) >> 3; sg = tid & 7;
      *(uint4*)&lVt[d][sg * 8] = *(const uint4*)(Vg + (size_t)d * 1024 + kt * 64 + sg * 8);
      if (tid < 64) {
        L = tid + 512; r = L / 9; s = L - r * 9;
        *(uint4*)&lK[r][s * 8] = *(const uint4*)(Kg + (size_t)(kt * 64 + r) * 3456 + s * 8);
        d = (tid + 512) >> 3;
        *(uint4*)&lVt[d][sg * 8] = *(const uint4*)(Vg + (size_t)d * 1024 + kt * 64 + sg * 8);
      }
    }
    __syncthreads();

    f32x4 sfr[4];
    __builtin_amdgcn_s_setprio(1);
    #pragma unroll
    for (int kb = 0; kb < 4; ++kb) {
      f32x4 sv = f32x4{0.f, 0.f, 0.f, 0.f};
      #pragma unroll
      for (int ks = 0; ks < 3; ++ks) {
        bf16x8 ak = *(const bf16x8*)&lK[kb * 16 + lr][ks * 32 + kg * 8];
        sv = MFMA16(ak, bq[ks], sv);
      }
      sfr[kb] = sv;
    }
    __builtin_amdgcn_s_setprio(0);

    float mx = sfr[0][0];
    #pragma unroll
    for (int kb = 0; kb < 4; ++kb)
      #pragma unroll
      for (int r = 0; r < 4; ++r) mx = fmaxf(mx, sfr[kb][r]);
    mx = fmaxf(mx, __shfl_xor(mx, 16));
    mx = fmaxf(mx, __shfl_xor(mx, 32));
    mx *= scale;
    float mn = fmaxf(mrun, mx);
    float al = __expf(mrun - mn);
    mrun = mn;
    float sum = 0.f;
    #pragma unroll
    for (int kb = 0; kb < 4; ++kb) {
      #pragma unroll
      for (int rp = 0; rp < 2; ++rp) {
        float p0 = __expf(__fmaf_rn(sfr[kb][2 * rp], scale, -mn));
        float p1 = __expf(__fmaf_rn(sfr[kb][2 * rp + 1], scale, -mn));
        sum += p0 + p1;
        u32 pk = (u32)f2bf(p0) | ((u32)f2bf(p1) << 16);
        *(u32*)&lPt[w][lr][kb * 16 + kg * 4 + rp * 2] = pk;
      }
    }
    sum += __shfl_xor(sum, 16);
    sum += __shfl_xor(sum, 32);
    lrun = lrun * al + sum;
    #pragma unroll
    for (int nd = 0; nd < 5; ++nd)
      #pragma unroll
      for (int r = 0; r < 4; ++r) oacc[nd][r] *= al;

    __builtin_amdgcn_s_setprio(1);
    #pragma unroll
    for (int s = 0; s < 2; ++s) {
      bf16x8 bp = *(const bf16x8*)&lPt[w][lr][s * 32 + kg * 8];
      #pragma unroll
      for (int nd = 0; nd < 5; ++nd) {
        bf16x8 av = *(const bf16x8*)&lVt[nd * 16 + lr][s * 32 + kg * 8];
        oacc[nd] = MFMA16(av, bp, oacc[nd]);
      }
    }
    __builtin_amdgcn_s_setprio(0);
  }

  float inv = 1.f / lrun;
  size_t orow = ((size_t)b * 1024 + qt * 64 + w * 16 + lr) * 1152 + h * 72;
  #pragma unroll
  for (int nd = 0; nd < 5; ++nd) {
    int d0 = nd * 16 + kg * 4;
    if (d0 < 72) {
      ushort4 u;
      u.x = f2bf(oacc[nd][0] * inv);
      u.y = f2bf(oacc[nd][1] * inv);
      u.z = f2bf(oacc[nd][2] * inv);
      u.w = f2bf(oacc[nd][3] * inv);
      *(ushort4*)&O[orow + d0] = u;
    }
  }
}

extern "C" void kernel_launch(void* const* d_in, const int* in_sizes, int n_in,
                              void* d_out, int out_size, void* d_ws, size_t ws_size,
                              hipStream_t stream) {
  const float* x     = (const float*)d_in[0];
  const float* c     = (const float*)d_in[1];
  const float* ln1_w = (const float*)d_in[2];
  const float* ln1_b = (const float*)d_in[3];
  const float* wq    = (const float*)d_in[4];
  const float* wk    = (const float*)d_in[5];
  const float* wv    = (const float*)d_in[6];
  const float* wo    = (const float*)d_in[7];
  const float* wo_b  = (const float*)d_in[8];
  const float* ln2_w = (const float*)d_in[9];
  const float* ln2_b = (const float*)d_in[10];
  const float* fc1_w = (const float*)d_in[11];
  const float* fc1_b = (const float*)d_in[12];
  const float* fc2_w = (const float*)d_in[13];
  const float* fc2_b = (const float*)d_in[14];
  const float* ada_w = (const float*)d_in[15];
  const float* ada_b = (const float*)d_in[16];
  float* out = (float*)d_out;

  char* base = (char*)d_ws;
  size_t off = 0;
  auto alloc = [&](size_t nbytes) -> void* {
    void* p = base + off;
    off += (nbytes + 255) & ~(size_t)255;
    return p;
  };
  const size_t MD = 8192ull * 1152;
  float* partial = (float*)alloc(64ull * 6912 * 4);
  float* modb   = (float*)alloc(55296 * 4);
  u16* qkvT = (u16*)alloc(3584ull * 1152 * 2);   // padded to 3584 rows
  u16* woT  = (u16*)alloc(1152ull * 1152 * 2);
  u16* fc1T = (u16*)alloc(4608ull * 1152 * 2);
  u16* fc2T = (u16*)alloc(1280ull * 4608 * 2);   // padded to 1280 rows
  u16* hbuf = (u16*)alloc(MD * 2);               // h -> attnO -> h2
  float* x1 = (float*)alloc(MD * 4);
  u16* vtb  = (u16*)alloc(128ull * 72 * 1024 * 2);
  u16* fc2p = (u16*)alloc(3ull * MD * 2);        // bf16 partials x3, stride 1152
  u16* big  = (u16*)alloc(8192ull * 4608 * 2);   // qkv (stride 3456) then m1
  u16* qkv = big;
  u16* m1 = big;
  // total ws ~243 MB (fits 256 MiB = 268.4 MB)

  k_modproj1<<<dim3(27, 8), 256, 0, stream>>>(c, ada_w, partial);
  k_modproj2<<<27, 256, 0, stream>>>(partial, ada_b, modb);
  k_tcvt<<<dim3(36, 36), 256, 0, stream>>>(wq, qkvT, 1152, 1152);
  k_tcvt<<<dim3(36, 36), 256, 0, stream>>>(wk, qkvT + 1152ull * 1152, 1152, 1152);
  k_tcvt<<<dim3(36, 36), 256, 0, stream>>>(wv, qkvT + 2304ull * 1152, 1152, 1152);
  k_tcvt<<<dim3(36, 36), 256, 0, stream>>>(wo, woT, 1152, 1152);
  k_tcvt<<<dim3(144, 36), 256, 0, stream>>>(fc1_w, fc1T, 1152, 4608);
  k_tcvt<<<dim3(36, 144), 256, 0, stream>>>(fc2_w, fc2T, 4608, 1152);

  // h = modulate(LN(x), sh_msa, sc_msa)
  k_lnmod<<<8192, 256, 0, stream>>>(x, ln1_w, ln1_b, modb, 0, 1152, hbuf);
  // qkv (4-phase): Q,K rows into qkv (stride 3456), V transposed into vtb
  k_gemm8p<3><<<dim3(14, 32), 512, 0, stream>>>(hbuf, qkvT, 1152, 1152, qkv, nullptr, vtb);
  // attention -> O (reuse hbuf)
  k_attn<<<2048, 256, 0, stream>>>(qkv, vtb, hbuf);
  // x1 = x + g_msa*(O@wo + wo_b)   (4-wave)
  k_gemm<1><<<dim3(9, 64), 256, 0, stream>>>(hbuf, woT, 1152, 1152, nullptr, x1, wo_b, x, modb, 2304, nullptr);
  // h2 = modulate(LN(x1), sh_mlp, sc_mlp)
  k_lnmod<<<8192, 256, 0, stream>>>(x1, ln2_w, ln2_b, modb, 3456, 4608, hbuf);
  // m1 = gelu(h2@fc1 + fc1_b)  (4-phase)
  k_gemm8p<2><<<dim3(18, 32), 512, 0, stream>>>(hbuf, fc1T, 1152, 1152, m1, fc1_b, nullptr);
  // fc2 split-K x3 (4-phase, klen=1536, 480 blocks) then fused reduce
  k_gemm8p<5><<<dim3(5, 32, 3), 512, 0, stream>>>(m1, fc2T, 4608, 1536, fc2p, nullptr, nullptr);
  k_fc2red<<<9216, 256, 0, stream>>>(fc2p, x1, fc2_b, modb, out);
}

// Round 17
// 538.106 us; speedup vs baseline: 1.0224x; 1.0224x over previous
//
#include <hip/hip_runtime.h>
#include <hip/hip_bf16.h>

// DiT block: B=8, S=1024, D=1152, H=16, HD=72, HID=4608
// k_gemm8p (r15 winner + compiler-scheduled lgkm waits): 256x256, 8 waves,
//   4-phase deduped-read schedule {vmcnt(8); bar; 12 ds_read; stage; setprio;
//   16 MFMA32 (compiler inserts fine-grained lgkmcnt)}. BK=64, LDS 128KB,
//   XOR swizzle. qkv (EPI3), fc1 (EPI2), fc2 split-K x3 (EPI5, klen=1536).
// k_gemm: 128^2 4-wave depth-3 counted (r11) for wo (EPI1).
// Attention: swapped QK^T, pre-transposed V, in-lane softmax.

typedef unsigned short u16;
typedef unsigned int u32;
typedef __attribute__((ext_vector_type(8))) short bf16x8;
typedef __attribute__((ext_vector_type(4))) float f32x4;
typedef __attribute__((ext_vector_type(16))) float f32x16;

#define MFMA16(a, b, c) __builtin_amdgcn_mfma_f32_16x16x32_bf16((a), (b), (c), 0, 0, 0)
#define MFMA32(a, b, c) __builtin_amdgcn_mfma_f32_32x32x16_bf16((a), (b), (c), 0, 0, 0)

__device__ __forceinline__ u16 f2bf(float f) {
  __hip_bfloat16 h = __float2bfloat16(f);
  return __builtin_bit_cast(u16, h);
}

__device__ __forceinline__ float bf2f(u16 u) {
  u32 v = ((u32)u) << 16;
  return __builtin_bit_cast(float, v);
}

__device__ __forceinline__ void gload16(const u16* g, u16* l) {
  __builtin_amdgcn_global_load_lds(
      (const __attribute__((address_space(1))) unsigned int*)(const void*)g,
      (__attribute__((address_space(3))) unsigned int*)(void*)l, 16, 0, 0);
}

// ------- mod projection, split-K stage 1 (silu fused) -------
__global__ __launch_bounds__(256) void k_modproj1(const float* __restrict__ cc,
                                                  const float* __restrict__ aw,
                                                  float* __restrict__ partial) {
  __shared__ float lc[8][144];
  int kc = blockIdx.y;
  for (int i = threadIdx.x; i < 1152; i += 256) {
    int b = i / 144, k = i % 144;
    float v = cc[b * 1152 + kc * 144 + k];
    lc[b][k] = v / (1.f + __expf(-v));
  }
  __syncthreads();
  int j = blockIdx.x * 256 + threadIdx.x;
  float acc[8] = {0, 0, 0, 0, 0, 0, 0, 0};
  for (int k = 0; k < 144; ++k) {
    float w = aw[(size_t)(kc * 144 + k) * 6912 + j];
    #pragma unroll
    for (int b = 0; b < 8; ++b) acc[b] += lc[b][k] * w;
  }
  #pragma unroll
  for (int b = 0; b < 8; ++b) partial[((size_t)kc * 8 + b) * 6912 + j] = acc[b];
}

// ------- mod projection stage 2 -------
__global__ __launch_bounds__(256) void k_modproj2(const float* __restrict__ partial,
                                                  const float* __restrict__ ab,
                                                  float* __restrict__ mo) {
  int j = blockIdx.x * 256 + threadIdx.x;
  float bias = ab[j];
  #pragma unroll
  for (int b = 0; b < 8; ++b) {
    float s = 0.f;
    #pragma unroll
    for (int kc = 0; kc < 8; ++kc) s += partial[((size_t)kc * 8 + b) * 6912 + j];
    mo[(size_t)b * 6912 + j] = s + bias;
  }
}

// ------- transpose-convert: in[K][N] f32 -> out[N][K] bf16 -------
__global__ __launch_bounds__(256) void k_tcvt(const float* __restrict__ in, u16* __restrict__ out,
                                              int K, int N) {
  __shared__ float t[32][33];
  int tx = threadIdx.x & 31, ty = threadIdx.x >> 5;
  size_t bx = (size_t)blockIdx.x * 32, by = (size_t)blockIdx.y * 32;
  #pragma unroll
  for (int i = 0; i < 4; ++i) t[ty + 8 * i][tx] = in[(by + ty + 8 * i) * N + bx + tx];
  __syncthreads();
  #pragma unroll
  for (int i = 0; i < 4; ++i) out[(bx + ty + 8 * i) * K + by + tx] = f2bf(t[tx][ty + 8 * i]);
}

// ------- fused LayerNorm + modulate -> bf16 row -------
__global__ __launch_bounds__(256) void k_lnmod(const float* __restrict__ xin,
                                               const float* __restrict__ w,
                                               const float* __restrict__ bs,
                                               const float* __restrict__ mo,
                                               int sh_off, int sc_off, u16* __restrict__ o) {
  int row = blockIdx.x;
  int b = row >> 10;
  int tid = threadIdx.x;
  const float4* x4 = (const float4*)(xin + (size_t)row * 1152);
  float4 v0 = x4[tid];
  float4 v1 = make_float4(0.f, 0.f, 0.f, 0.f);
  if (tid < 32) v1 = x4[256 + tid];
  float s = v0.x + v0.y + v0.z + v0.w + v1.x + v1.y + v1.z + v1.w;
  float sq = v0.x * v0.x + v0.y * v0.y + v0.z * v0.z + v0.w * v0.w +
             v1.x * v1.x + v1.y * v1.y + v1.z * v1.z + v1.w * v1.w;
  #pragma unroll
  for (int d = 32; d > 0; d >>= 1) { s += __shfl_down(s, d); sq += __shfl_down(sq, d); }
  __shared__ float ps[4], pq[4];
  int wid = tid >> 6, lane = tid & 63;
  if (lane == 0) { ps[wid] = s; pq[wid] = sq; }
  __syncthreads();
  float S = ps[0] + ps[1] + ps[2] + ps[3];
  float SQ = pq[0] + pq[1] + pq[2] + pq[3];
  float mean = S * (1.f / 1152.f);
  float var = SQ * (1.f / 1152.f) - mean * mean;
  float rs = rsqrtf(var + 1e-5f);
  const float* shp = mo + (size_t)b * 6912 + sh_off;
  const float* scp = mo + (size_t)b * 6912 + sc_off;
  u16* orow = o + (size_t)row * 1152;
  {
    int col = 4 * tid;
    ushort4 u; float y;
    y = (v0.x - mean) * rs * w[col + 0] + bs[col + 0]; u.x = f2bf(y * (1.f + scp[col + 0]) + shp[col + 0]);
    y = (v0.y - mean) * rs * w[col + 1] + bs[col + 1]; u.y = f2bf(y * (1.f + scp[col + 1]) + shp[col + 1]);
    y = (v0.z - mean) * rs * w[col + 2] + bs[col + 2]; u.z = f2bf(y * (1.f + scp[col + 2]) + shp[col + 2]);
    y = (v0.w - mean) * rs * w[col + 3] + bs[col + 3]; u.w = f2bf(y * (1.f + scp[col + 3]) + shp[col + 3]);
    *(ushort4*)&orow[col] = u;
  }
  if (tid < 32) {
    int col = 1024 + 4 * tid;
    ushort4 u; float y;
    y = (v1.x - mean) * rs * w[col + 0] + bs[col + 0]; u.x = f2bf(y * (1.f + scp[col + 0]) + shp[col + 0]);
    y = (v1.y - mean) * rs * w[col + 1] + bs[col + 1]; u.y = f2bf(y * (1.f + scp[col + 1]) + shp[col + 1]);
    y = (v1.z - mean) * rs * w[col + 2] + bs[col + 2]; u.z = f2bf(y * (1.f + scp[col + 2]) + shp[col + 2]);
    y = (v1.w - mean) * rs * w[col + 3] + bs[col + 3]; u.w = f2bf(y * (1.f + scp[col + 3]) + shp[col + 3]);
    *(ushort4*)&orow[col] = u;
  }
}

// ======= 4-PHASE GEMM (r15 order, compiler lgkm): BM=BN=256, 512 thr, BK=64 =======
// klen must be a multiple of 128. Phase = {VM(8); bar; 12 deduped reads; stage;
// setprio; 16 MFMA32 (compiler-inserted fine-grained lgkm waits)}.
// EPI 2: gelu, stride gridDim.x*256 (fc1)
// EPI 3: QKV (Q,K stride 3456; V transposed to vt)
// EPI 5: bf16 partial, stride 1152, guard gcol<1152, z-offset (fc2 split-K)
template <int EPI>
__global__ __launch_bounds__(512, 2) void k_gemm8p(const u16* __restrict__ A,
                                                   const u16* __restrict__ Bt,
                                                   int Kst, int klen,
                                                   u16* __restrict__ Cb,
                                                   const float* __restrict__ bias,
                                                   u16* __restrict__ vt) {
  const int tid = threadIdx.x;
  const int w = tid >> 6, lane = tid & 63;
  const int wm = w >> 2, wn = w & 3;
  const int l31 = lane & 31, hi = lane >> 5;

  const int nwg = gridDim.x * gridDim.y;
  const int id = blockIdx.y * gridDim.x + blockIdx.x;
  const int swz = (id & 7) * (nwg >> 3) + (id >> 3);
  const int tM = (swz / gridDim.x) * 256, tN = (swz % gridDim.x) * 256;
  const int koff = blockIdx.z * klen;

  __shared__ u16 lA[2][2][256 * 32];
  __shared__ u16 lB[2][2][256 * 32];
  f32x16 acc[4][2];
  #pragma unroll
  for (int m = 0; m < 4; ++m)
    #pragma unroll
    for (int n = 0; n < 2; ++n)
      #pragma unroll
      for (int r = 0; r < 16; ++r) acc[m][n][r] = 0.f;

  const int lrow = lane >> 2, lseg = lane & 3;
  const int fl = (lrow & 3) ^ ((lrow >> 2) & 3);
  const u16* gA = A + (size_t)(tM + w * 32 + lrow) * Kst + (lseg ^ fl) * 8 + koff;
  const u16* gB = Bt + (size_t)(tN + w * 32 + lrow) * Kst + (lseg ^ fl) * 8 + koff;
  const size_t rstep = (size_t)16 * Kst;
  const int wo0 = (w * 32) * 32, wo1 = (w * 32 + 16) * 32;
  const int fr = (l31 & 3) ^ ((l31 >> 2) & 3);
  const int c0 = (hi ^ fr) * 8;
  const int c1 = ((hi ^ fr) ^ 2) * 8;
  const int arow = (wm * 128 + l31) * 32;
  const int brow = (wn * 64 + l31) * 32;

#define SA(BUF, KH, KO)                                       \
  do {                                                        \
    gload16(gA + (KO), &lA[BUF][KH][wo0]);                    \
    gload16(gA + rstep + (KO), &lA[BUF][KH][wo1]);            \
  } while (0)
#define SB(BUF, KH, KO)                                       \
  do {                                                        \
    gload16(gB + (KO), &lB[BUF][KH][wo0]);                    \
    gload16(gB + rstep + (KO), &lB[BUF][KH][wo1]);            \
  } while (0)
#define VM(Nst) asm volatile("s_waitcnt vmcnt(" #Nst ")" ::: "memory")

// phase: vmcnt handled by caller; barrier (+pin) -> deduped reads -> stage ->
// MFMA cluster with COMPILER-scheduled lgkm waits (no forced drain).
#define PHASE(CB, KH, STAGE_STMT)                                               \
  do {                                                                          \
    __builtin_amdgcn_s_barrier();                                               \
    __builtin_amdgcn_sched_barrier(0);                                          \
    bf16x8 af[4][2], bf[2][2];                                                  \
    _Pragma("unroll")                                                           \
    for (int m_ = 0; m_ < 4; ++m_) {                                            \
      af[m_][0] = *(const bf16x8*)&lA[CB][KH][arow + m_ * 1024 + c0];           \
      af[m_][1] = *(const bf16x8*)&lA[CB][KH][arow + m_ * 1024 + c1];           \
    }                                                                           \
    _Pragma("unroll")                                                           \
    for (int n_ = 0; n_ < 2; ++n_) {                                            \
      bf[n_][0] = *(const bf16x8*)&lB[CB][KH][brow + n_ * 1024 + c0];           \
      bf[n_][1] = *(const bf16x8*)&lB[CB][KH][brow + n_ * 1024 + c1];           \
    }                                                                           \
    STAGE_STMT;                                                                 \
    __builtin_amdgcn_s_setprio(1);                                              \
    _Pragma("unroll")                                                           \
    for (int m_ = 0; m_ < 4; ++m_)                                              \
      _Pragma("unroll")                                                         \
      for (int n_ = 0; n_ < 2; ++n_)                                            \
        acc[m_][n_] = MFMA32(af[m_][0], bf[n_][0], acc[m_][n_]);                \
    _Pragma("unroll")                                                           \
    for (int m_ = 0; m_ < 4; ++m_)                                              \
      _Pragma("unroll")                                                         \
      for (int n_ = 0; n_ < 2; ++n_)                                            \
        acc[m_][n_] = MFMA32(af[m_][1], bf[n_][1], acc[m_][n_]);                \
    __builtin_amdgcn_s_setprio(0);                                              \
  } while (0)

  const int NIT = klen >> 7;
  // prologue: 3 slots = 12 gloads in flight
  SA(0, 0, 0); SB(0, 0, 0);
  SA(0, 1, 32); SB(0, 1, 32);
  SA(1, 0, 64); SB(1, 0, 64);
  for (int it = 0; it < NIT - 1; ++it) {
    const int kb = it * 128;
    VM(8); PHASE(0, 0, { SA(1, 1, kb + 96);  SB(1, 1, kb + 96);  });
    VM(8); PHASE(0, 1, { SA(0, 0, kb + 128); SB(0, 0, kb + 128); });
    VM(8); PHASE(1, 0, { SA(0, 1, kb + 160); SB(0, 1, kb + 160); });
    VM(8); PHASE(1, 1, { SA(1, 0, kb + 192); SB(1, 0, kb + 192); });
  }
  {  // tail: stage only the final slot; drain 8 -> 8 -> 4 -> 0
    const int kb = (NIT - 1) * 128;
    VM(8); PHASE(0, 0, { SA(1, 1, kb + 96); SB(1, 1, kb + 96); });
    VM(8); PHASE(0, 1, (void)0);
    VM(4); PHASE(1, 0, (void)0);
    VM(0); PHASE(1, 1, (void)0);
  }
#undef SA
#undef SB
#undef VM
#undef PHASE

  // epilogue: 32x32 D layout: col = lane&31, row = (reg&3) + 8*(reg>>2) + 4*(lane>>5)
  #pragma unroll
  for (int m = 0; m < 4; ++m)
    #pragma unroll
    for (int n = 0; n < 2; ++n) {
      int gcol = tN + wn * 64 + n * 32 + l31;
      #pragma unroll
      for (int q = 0; q < 4; ++q) {
        int grow0 = tM + wm * 128 + m * 32 + hi * 4 + q * 8;
        if (EPI == 3) {
          if (gcol < 2304) {
            #pragma unroll
            for (int r = 0; r < 4; ++r)
              Cb[(size_t)(grow0 + r) * 3456 + gcol] = f2bf(acc[m][n][q * 4 + r]);
          } else if (gcol < 3456) {
            int qq = gcol - 2304;
            int hh = qq / 72;
            int d = qq - hh * 72;
            int bb = grow0 >> 10, sl = grow0 & 1023;
            ushort4 u;
            u.x = f2bf(acc[m][n][q * 4 + 0]); u.y = f2bf(acc[m][n][q * 4 + 1]);
            u.z = f2bf(acc[m][n][q * 4 + 2]); u.w = f2bf(acc[m][n][q * 4 + 3]);
            *(ushort4*)&vt[(((size_t)bb * 16 + hh) * 72 + d) * 1024 + sl] = u;
          }
        } else if (EPI == 5) {
          if (gcol < 1152) {
            u16* Po = Cb + (size_t)blockIdx.z * 9437184ull;  // 8192*1152
            #pragma unroll
            for (int r = 0; r < 4; ++r)
              Po[(size_t)(grow0 + r) * 1152 + gcol] = f2bf(acc[m][n][q * 4 + r]);
          }
        } else {  // EPI 2: fast gelu
          const int NC = gridDim.x * 256;
          float bi = bias[gcol];
          #pragma unroll
          for (int r = 0; r < 4; ++r) {
            float z = acc[m][n][q * 4 + r] + bi;
            float z2 = z * z;
            float u = z * __fmaf_rn(z2, -0.0713548162f, -1.5957691216f);
            float e = __expf(u);
            Cb[(size_t)(grow0 + r) * NC + gcol] = f2bf(z * __builtin_amdgcn_rcpf(1.f + e));
          }
        }
      }
    }
}

// ------- 128x128 4-wave GEMM (r11, for wo): 32x32 frags, depth-3 counted-vmcnt -------
template <int EPI>
__global__ __launch_bounds__(256) void k_gemm(const u16* __restrict__ A, const u16* __restrict__ Bt,
                                              int Kst, int klen, u16* __restrict__ Cb,
                                              float* __restrict__ Cf,
                                              const float* __restrict__ bias,
                                              const float* __restrict__ res,
                                              const float* __restrict__ mo, int goff,
                                              u16* __restrict__ vt) {
  const int tid = threadIdx.x;
  const int w = tid >> 6, lane = tid & 63;
  const int wr = w >> 1, wc = w & 1;
  const int l31 = lane & 31, hi = lane >> 5;

  const int nwg = gridDim.x * gridDim.y;
  const int id = blockIdx.y * gridDim.x + blockIdx.x;
  const int swz = (id & 7) * (nwg >> 3) + (id >> 3);
  const int tM = (swz / gridDim.x) * 128, tN = (swz % gridDim.x) * 128;
  const int N = gridDim.x * 128;
  const int koff = blockIdx.z * klen;

  __shared__ u16 lA[3][128 * 32];
  __shared__ u16 lB[3][128 * 32];
  f32x16 acc[2][2];
  #pragma unroll
  for (int m = 0; m < 2; ++m)
    #pragma unroll
    for (int n = 0; n < 2; ++n)
      #pragma unroll
      for (int r = 0; r < 16; ++r) acc[m][n][r] = 0.f;

  const int lrow = lane >> 2, lseg = lane & 3;
  const int fl = (lrow & 3) ^ ((lrow >> 2) & 3);
  const u16* gA = A + (size_t)(tM + w * 32 + lrow) * Kst + (lseg ^ fl) * 8 + koff;
  const u16* gB = Bt + (size_t)(tN + w * 32 + lrow) * Kst + (lseg ^ fl) * 8 + koff;
  const size_t rstep = (size_t)16 * Kst;
  const int wo0 = (w * 32) * 32, wo1 = (w * 32 + 16) * 32;
  const int fr = (l31 & 3) ^ ((l31 >> 2) & 3);
  const int c0 = (hi ^ fr) * 8;
  const int c1 = ((hi ^ fr) ^ 2) * 8;
  const int arow = (wr * 64 + l31) * 32;
  const int brow = (wc * 64 + l31) * 32;

#define STAGE(buf, ks)                        \
  do {                                        \
    gload16(gA + (ks), lA[buf] + wo0);        \
    gload16(gA + rstep + (ks), lA[buf] + wo1);\
    gload16(gB + (ks), lB[buf] + wo0);        \
    gload16(gB + rstep + (ks), lB[buf] + wo1);\
  } while (0)

#define COMPUTE(buf)                                                            \
  do {                                                                          \
    bf16x8 a00 = *(const bf16x8*)&lA[buf][arow + c0];                           \
    bf16x8 a01 = *(const bf16x8*)&lA[buf][arow + c1];                           \
    bf16x8 a10 = *(const bf16x8*)&lA[buf][arow + 1024 + c0];                    \
    bf16x8 a11 = *(const bf16x8*)&lA[buf][arow + 1024 + c1];                    \
    bf16x8 b00 = *(const bf16x8*)&lB[buf][brow + c0];                           \
    bf16x8 b01 = *(const bf16x8*)&lB[buf][brow + c1];                           \
    bf16x8 b10 = *(const bf16x8*)&lB[buf][brow + 1024 + c0];                    \
    bf16x8 b11 = *(const bf16x8*)&lB[buf][brow + 1024 + c1];                    \
    __builtin_amdgcn_s_setprio(1);                                              \
    acc[0][0] = MFMA32(a00, b00, acc[0][0]);                                    \
    acc[0][1] = MFMA32(a00, b10, acc[0][1]);                                    \
    acc[1][0] = MFMA32(a10, b00, acc[1][0]);                                    \
    acc[1][1] = MFMA32(a10, b10, acc[1][1]);                                    \
    acc[0][0] = MFMA32(a01, b01, acc[0][0]);                                    \
    acc[0][1] = MFMA32(a01, b11, acc[0][1]);                                    \
    acc[1][0] = MFMA32(a11, b01, acc[1][0]);                                    \
    acc[1][1] = MFMA32(a11, b11, acc[1][1]);                                    \
    __builtin_amdgcn_s_setprio(0);                                              \
  } while (0)

#define WAITBAR(Nst)                                          \
  do {                                                        \
    asm volatile("s_waitcnt vmcnt(" #Nst ")" ::: "memory");   \
    __builtin_amdgcn_s_barrier();                             \
    __builtin_amdgcn_sched_barrier(0);                        \
  } while (0)

  const int nt = klen >> 5;
  STAGE(0, 0);
  STAGE(1, 32);
  int ks = 64;
  for (int g = 0; g < nt / 3 - 1; ++g) {
    WAITBAR(4); STAGE(2, ks);      COMPUTE(0);
    WAITBAR(4); STAGE(0, ks + 32); COMPUTE(1);
    WAITBAR(4); STAGE(1, ks + 64); COMPUTE(2);
    ks += 96;
  }
  WAITBAR(4); STAGE(2, ks); COMPUTE(0);
  WAITBAR(4); COMPUTE(1);
  WAITBAR(0); COMPUTE(2);
#undef STAGE
#undef COMPUTE
#undef WAITBAR

  #pragma unroll
  for (int m = 0; m < 2; ++m)
    #pragma unroll
    for (int n = 0; n < 2; ++n) {
      int gcol = tN + wc * 64 + n * 32 + l31;
      #pragma unroll
      for (int q = 0; q < 4; ++q) {
        int grow0 = tM + wr * 64 + m * 32 + hi * 4 + q * 8;
        float g = mo[(size_t)(grow0 >> 10) * 6912 + goff + gcol];
        float bi = bias[gcol];
        #pragma unroll
        for (int r = 0; r < 4; ++r) {
          size_t idx = (size_t)(grow0 + r) * N + gcol;
          Cf[idx] = res[idx] + g * (acc[m][n][q * 4 + r] + bi);
        }
      }
    }
}

// ------- fc2 split-K x3 reduce: out = x1 + g_mlp*(p0+p1+p2+bias); stride 1152 -------
__global__ __launch_bounds__(256) void k_fc2red(const u16* __restrict__ p,
                                                const float* __restrict__ x1,
                                                const float* __restrict__ bias,
                                                const float* __restrict__ mo,
                                                float* __restrict__ out) {
  size_t i = ((size_t)blockIdx.x * 256 + threadIdx.x) * 4;
  int row = (int)(i / 1152);
  int col = (int)(i - (size_t)row * 1152);
  int b = row >> 10;
  ushort4 a0 = *(const ushort4*)(p + i);
  ushort4 a1 = *(const ushort4*)(p + 9437184ull + i);
  ushort4 a2 = *(const ushort4*)(p + 18874368ull + i);
  float4 r = *(const float4*)(x1 + i);
  const float* gp = mo + (size_t)b * 6912 + 5760 + col;
  const float* bp = bias + col;
  float4 o;
  o.x = r.x + gp[0] * (bf2f(a0.x) + bf2f(a1.x) + bf2f(a2.x) + bp[0]);
  o.y = r.y + gp[1] * (bf2f(a0.y) + bf2f(a1.y) + bf2f(a2.y) + bp[1]);
  o.z = r.z + gp[2] * (bf2f(a0.z) + bf2f(a1.z) + bf2f(a2.z) + bp[2]);
  o.w = r.w + gp[3] * (bf2f(a0.w) + bf2f(a1.w) + bf2f(a2.w) + bp[3]);
  *(float4*)(out + i) = o;
}

// ------- flash attention, swapped-QK^T structure -------
__global__ __launch_bounds__(256) void k_attn(const u16* __restrict__ QKV, const u16* __restrict__ Vt,
                                              u16* __restrict__ O) {
  const int tid = threadIdx.x;
  const int w = tid >> 6, lane = tid & 63;
  const int lr = lane & 15, kg = lane >> 4;
  int bx = blockIdx.x;
  bx = (bx & 7) * 256 + (bx >> 3);
  const int qt = bx & 15, h = (bx >> 4) & 15, b = bx >> 8;

  __shared__ u16 lQ[64][104];
  __shared__ u16 lK[64][104];
  __shared__ u16 lVt[80][72];
  __shared__ u16 lPt[4][16][72];

  const size_t qkbase = (size_t)b * 1024 * 3456 + (size_t)h * 72;
  const u16* Qg = QKV + qkbase;
  const u16* Kg = QKV + qkbase + 1152;
  const u16* Vg = Vt + ((size_t)(b * 16 + h) * 72) * 1024;

  const uint4 z4 = make_uint4(0, 0, 0, 0);
  for (int L = tid; L < 192; L += 256) {
    int r = L / 3, s = L - (L / 3) * 3;
    *(uint4*)&lQ[r][72 + s * 8] = z4;
    *(uint4*)&lK[r][72 + s * 8] = z4;
  }
  for (int L = tid; L < 72; L += 256) {
    int r = L / 9, s = L - (L / 9) * 9;
    *(uint4*)&lVt[72 + r][s * 8] = z4;
  }
  {
    int L = tid; int r = L / 9, s = L - r * 9;
    *(uint4*)&lQ[r][s * 8] = *(const uint4*)(Qg + (size_t)(qt * 64 + r) * 3456 + s * 8);
    L = tid + 256; r = L / 9; s = L - r * 9;
    *(uint4*)&lQ[r][s * 8] = *(const uint4*)(Qg + (size_t)(qt * 64 + r) * 3456 + s * 8);
    if (tid < 64) {
      L = tid + 512; r = L / 9; s = L - r * 9;
      *(uint4*)&lQ[r][s * 8] = *(const uint4*)(Qg + (size_t)(qt * 64 + r) * 3456 + s * 8);
    }
  }
  __syncthreads();

  bf16x8 bq[3];
  #pragma unroll
  for (int ks = 0; ks < 3; ++ks) bq[ks] = *(const bf16x8*)&lQ[w * 16 + lr][ks * 32 + kg * 8];

  const float scale = 0.11785113019775793f;  // 1/sqrt(72)
  float mrun = -1e30f, lrun = 0.f;
  f32x4 oacc[5];
  #pragma unroll
  for (int nd = 0; nd < 5; ++nd) oacc[nd] = f32x4{0.f, 0.f, 0.f, 0.f};

  for (int kt = 0; kt < 16; ++kt) {
    __syncthreads();
    {
      int L = tid; int r = L / 9, s = L - (L / 9) * 9;
      *(uint4*)&lK[r][s * 8] = *(const uint4*)(Kg + (size_t)(kt * 64 + r) * 3456 + s * 8);
      int d = tid >> 3, sg = tid & 7;
      *(uint4*)&lVt[d][sg * 8] = *(const uint4*)(Vg + (size_t)d * 1024 + kt * 64 + sg * 8);
      L = tid + 256; r = L / 9; s = L - r * 9;
      *(uint4*)&lK[r][s * 8] = *(const uint4*)(Kg + (size_t)(kt * 64 + r) * 3456 + s * 8);
      d = (tid + 256) >> 3; sg = tid & 7;
      *(uint4*)&lVt[d][sg * 8] = *(const uint4*)(Vg + (size_t)d * 1024 + kt * 64 + sg * 8);
      if (tid < 64) {
        L = tid + 512; r = L / 9; s = L - r * 9;
        *(uint4*)&lK[r][s * 8] = *(const uint4*)(Kg + (size_t)(kt * 64 + r) * 3456 + s * 8);
        d = (tid + 512) >> 3;
        *(uint4*)&lVt[d][sg * 8] = *(const uint4*)(Vg + (size_t)d * 1024 + kt * 64 + sg * 8);
      }
    }
    __syncthreads();

    f32x4 sfr[4];
    __builtin_amdgcn_s_setprio(1);
    #pragma unroll
    for (int kb = 0; kb < 4; ++kb) {
      f32x4 sv = f32x4{0.f, 0.f, 0.f, 0.f};
      #pragma unroll
      for (int ks = 0; ks < 3; ++ks) {
        bf16x8 ak = *(const bf16x8*)&lK[kb * 16 + lr][ks * 32 + kg * 8];
        sv = MFMA16(ak, bq[ks], sv);
      }
      sfr[kb] = sv;
    }
    __builtin_amdgcn_s_setprio(0);

    float mx = sfr[0][0];
    #pragma unroll
    for (int kb = 0; kb < 4; ++kb)
      #pragma unroll
      for (int r = 0; r < 4; ++r) mx = fmaxf(mx, sfr[kb][r]);
    mx = fmaxf(mx, __shfl_xor(mx, 16));
    mx = fmaxf(mx, __shfl_xor(mx, 32));
    mx *= scale;
    float mn = fmaxf(mrun, mx);
    float al = __expf(mrun - mn);
    mrun = mn;
    float sum = 0.f;
    #pragma unroll
    for (int kb = 0; kb < 4; ++kb) {
      #pragma unroll
      for (int rp = 0; rp < 2; ++rp) {
        float p0 = __expf(__fmaf_rn(sfr[kb][2 * rp], scale, -mn));
        float p1 = __expf(__fmaf_rn(sfr[kb][2 * rp + 1], scale, -mn));
        sum += p0 + p1;
        u32 pk = (u32)f2bf(p0) | ((u32)f2bf(p1) << 16);
        *(u32*)&lPt[w][lr][kb * 16 + kg * 4 + rp * 2] = pk;
      }
    }
    sum += __shfl_xor(sum, 16);
    sum += __shfl_xor(sum, 32);
    lrun = lrun * al + sum;
    #pragma unroll
    for (int nd = 0; nd < 5; ++nd)
      #pragma unroll
      for (int r = 0; r < 4; ++r) oacc[nd][r] *= al;

    __builtin_amdgcn_s_setprio(1);
    #pragma unroll
    for (int s = 0; s < 2; ++s) {
      bf16x8 bp = *(const bf16x8*)&lPt[w][lr][s * 32 + kg * 8];
      #pragma unroll
      for (int nd = 0; nd < 5; ++nd) {
        bf16x8 av = *(const bf16x8*)&lVt[nd * 16 + lr][s * 32 + kg * 8];
        oacc[nd] = MFMA16(av, bp, oacc[nd]);
      }
    }
    __builtin_amdgcn_s_setprio(0);
  }

  float inv = 1.f / lrun;
  size_t orow = ((size_t)b * 1024 + qt * 64 + w * 16 + lr) * 1152 + h * 72;
  #pragma unroll
  for (int nd = 0; nd < 5; ++nd) {
    int d0 = nd * 16 + kg * 4;
    if (d0 < 72) {
      ushort4 u;
      u.x = f2bf(oacc[nd][0] * inv);
      u.y = f2bf(oacc[nd][1] * inv);
      u.z = f2bf(oacc[nd][2] * inv);
      u.w = f2bf(oacc[nd][3] * inv);
      *(ushort4*)&O[orow + d0] = u;
    }
  }
}

extern "C" void kernel_launch(void* const* d_in, const int* in_sizes, int n_in,
                              void* d_out, int out_size, void* d_ws, size_t ws_size,
                              hipStream_t stream) {
  const float* x     = (const float*)d_in[0];
  const float* c     = (const float*)d_in[1];
  const float* ln1_w = (const float*)d_in[2];
  const float* ln1_b = (const float*)d_in[3];
  const float* wq    = (const float*)d_in[4];
  const float* wk    = (const float*)d_in[5];
  const float* wv    = (const float*)d_in[6];
  const float* wo    = (const float*)d_in[7];
  const float* wo_b  = (const float*)d_in[8];
  const float* ln2_w = (const float*)d_in[9];
  const float* ln2_b = (const float*)d_in[10];
  const float* fc1_w = (const float*)d_in[11];
  const float* fc1_b = (const float*)d_in[12];
  const float* fc2_w = (const float*)d_in[13];
  const float* fc2_b = (const float*)d_in[14];
  const float* ada_w = (const float*)d_in[15];
  const float* ada_b = (const float*)d_in[16];
  float* out = (float*)d_out;

  char* base = (char*)d_ws;
  size_t off = 0;
  auto alloc = [&](size_t nbytes) -> void* {
    void* p = base + off;
    off += (nbytes + 255) & ~(size_t)255;
    return p;
  };
  const size_t MD = 8192ull * 1152;
  float* partial = (float*)alloc(64ull * 6912 * 4);
  float* modb   = (float*)alloc(55296 * 4);
  u16* qkvT = (u16*)alloc(3584ull * 1152 * 2);   // padded to 3584 rows
  u16* woT  = (u16*)alloc(1152ull * 1152 * 2);
  u16* fc1T = (u16*)alloc(4608ull * 1152 * 2);
  u16* fc2T = (u16*)alloc(1280ull * 4608 * 2);   // padded to 1280 rows
  u16* hbuf = (u16*)alloc(MD * 2);               // h -> attnO -> h2
  float* x1 = (float*)alloc(MD * 4);
  u16* vtb  = (u16*)alloc(128ull * 72 * 1024 * 2);
  u16* fc2p = (u16*)alloc(3ull * MD * 2);        // bf16 partials x3, stride 1152
  u16* big  = (u16*)alloc(8192ull * 4608 * 2);   // qkv (stride 3456) then m1
  u16* qkv = big;
  u16* m1 = big;
  // total ws ~243 MB (fits 256 MiB = 268.4 MB)

  k_modproj1<<<dim3(27, 8), 256, 0, stream>>>(c, ada_w, partial);
  k_modproj2<<<27, 256, 0, stream>>>(partial, ada_b, modb);
  k_tcvt<<<dim3(36, 36), 256, 0, stream>>>(wq, qkvT, 1152, 1152);
  k_tcvt<<<dim3(36, 36), 256, 0, stream>>>(wk, qkvT + 1152ull * 1152, 1152, 1152);
  k_tcvt<<<dim3(36, 36), 256, 0, stream>>>(wv, qkvT + 2304ull * 1152, 1152, 1152);
  k_tcvt<<<dim3(36, 36), 256, 0, stream>>>(wo, woT, 1152, 1152);
  k_tcvt<<<dim3(144, 36), 256, 0, stream>>>(fc1_w, fc1T, 1152, 4608);
  k_tcvt<<<dim3(36, 144), 256, 0, stream>>>(fc2_w, fc2T, 4608, 1152);

  // h = modulate(LN(x), sh_msa, sc_msa)
  k_lnmod<<<8192, 256, 0, stream>>>(x, ln1_w, ln1_b, modb, 0, 1152, hbuf);
  // qkv (4-phase): Q,K rows into qkv (stride 3456), V transposed into vtb
  k_gemm8p<3><<<dim3(14, 32), 512, 0, stream>>>(hbuf, qkvT, 1152, 1152, qkv, nullptr, vtb);
  // attention -> O (reuse hbuf)
  k_attn<<<2048, 256, 0, stream>>>(qkv, vtb, hbuf);
  // x1 = x + g_msa*(O@wo + wo_b)   (4-wave)
  k_gemm<1><<<dim3(9, 64), 256, 0, stream>>>(hbuf, woT, 1152, 1152, nullptr, x1, wo_b, x, modb, 2304, nullptr);
  // h2 = modulate(LN(x1), sh_mlp, sc_mlp)
  k_lnmod<<<8192, 256, 0, stream>>>(x1, ln2_w, ln2_b, modb, 3456, 4608, hbuf);
  // m1 = gelu(h2@fc1 + fc1_b)  (4-phase)
  k_gemm8p<2><<<dim3(18, 32), 512, 0, stream>>>(hbuf, fc1T, 1152, 1152, m1, fc1_b, nullptr);
  // fc2 split-K x3 (4-phase, klen=1536, 480 blocks) then fused reduce
  k_gemm8p<5><<<dim3(5, 32, 3), 512, 0, stream>>>(m1, fc2T, 4608, 1536, fc2p, nullptr, nullptr);
  k_fc2red<<<9216, 256, 0, stream>>>(fc2p, x1, fc2_b, modb, out);
}

// Round 18
// 534.210 us; speedup vs baseline: 1.0299x; 1.0073x over previous
//
#include <hip/hip_runtime.h>
#include <hip/hip_bf16.h>

// DiT block: B=8, S=1024, D=1152, H=16, HD=72, HID=4608
// k_gemm8p (r17 best): 256x256, 8 waves, 4-phase deduped-read schedule
//   {vmcnt(8); bar; 12 ds_read; stage; setprio; 16 MFMA32 (compiler lgkm)}.
//   BK=64, LDS 128KB, XOR swizzle. qkv (EPI3), fc1 (EPI2), fc2 split-K x3 (EPI5).
// k_gemm: 128^2 4-wave depth-3 counted (r11) for wo (EPI1).
// Attention: swapped QK^T, pre-transposed V, in-lane softmax.
// r18: batched square tcvt (1 launch, z=0..3), grid-strided fc2red.

typedef unsigned short u16;
typedef unsigned int u32;
typedef __attribute__((ext_vector_type(8))) short bf16x8;
typedef __attribute__((ext_vector_type(4))) float f32x4;
typedef __attribute__((ext_vector_type(16))) float f32x16;

#define MFMA16(a, b, c) __builtin_amdgcn_mfma_f32_16x16x32_bf16((a), (b), (c), 0, 0, 0)
#define MFMA32(a, b, c) __builtin_amdgcn_mfma_f32_32x32x16_bf16((a), (b), (c), 0, 0, 0)

__device__ __forceinline__ u16 f2bf(float f) {
  __hip_bfloat16 h = __float2bfloat16(f);
  return __builtin_bit_cast(u16, h);
}

__device__ __forceinline__ float bf2f(u16 u) {
  u32 v = ((u32)u) << 16;
  return __builtin_bit_cast(float, v);
}

__device__ __forceinline__ void gload16(const u16* g, u16* l) {
  __builtin_amdgcn_global_load_lds(
      (const __attribute__((address_space(1))) unsigned int*)(const void*)g,
      (__attribute__((address_space(3))) unsigned int*)(void*)l, 16, 0, 0);
}

// ------- mod projection, split-K stage 1 (silu fused) -------
__global__ __launch_bounds__(256) void k_modproj1(const float* __restrict__ cc,
                                                  const float* __restrict__ aw,
                                                  float* __restrict__ partial) {
  __shared__ float lc[8][144];
  int kc = blockIdx.y;
  for (int i = threadIdx.x; i < 1152; i += 256) {
    int b = i / 144, k = i % 144;
    float v = cc[b * 1152 + kc * 144 + k];
    lc[b][k] = v / (1.f + __expf(-v));
  }
  __syncthreads();
  int j = blockIdx.x * 256 + threadIdx.x;
  float acc[8] = {0, 0, 0, 0, 0, 0, 0, 0};
  for (int k = 0; k < 144; ++k) {
    float w = aw[(size_t)(kc * 144 + k) * 6912 + j];
    #pragma unroll
    for (int b = 0; b < 8; ++b) acc[b] += lc[b][k] * w;
  }
  #pragma unroll
  for (int b = 0; b < 8; ++b) partial[((size_t)kc * 8 + b) * 6912 + j] = acc[b];
}

// ------- mod projection stage 2 -------
__global__ __launch_bounds__(256) void k_modproj2(const float* __restrict__ partial,
                                                  const float* __restrict__ ab,
                                                  float* __restrict__ mo) {
  int j = blockIdx.x * 256 + threadIdx.x;
  float bias = ab[j];
  #pragma unroll
  for (int b = 0; b < 8; ++b) {
    float s = 0.f;
    #pragma unroll
    for (int kc = 0; kc < 8; ++kc) s += partial[((size_t)kc * 8 + b) * 6912 + j];
    mo[(size_t)b * 6912 + j] = s + bias;
  }
}

// ------- transpose-convert: in[K][N] f32 -> out[N][K] bf16 -------
__device__ __forceinline__ void tcvt_body(const float* __restrict__ in, u16* __restrict__ out,
                                          int K, int N) {
  __shared__ float t[32][33];
  int tx = threadIdx.x & 31, ty = threadIdx.x >> 5;
  size_t bx = (size_t)blockIdx.x * 32, by = (size_t)blockIdx.y * 32;
  #pragma unroll
  for (int i = 0; i < 4; ++i) t[ty + 8 * i][tx] = in[(by + ty + 8 * i) * N + bx + tx];
  __syncthreads();
  #pragma unroll
  for (int i = 0; i < 4; ++i) out[(bx + ty + 8 * i) * K + by + tx] = f2bf(t[tx][ty + 8 * i]);
}

__global__ __launch_bounds__(256) void k_tcvt(const float* __restrict__ in, u16* __restrict__ out,
                                              int K, int N) {
  tcvt_body(in, out, K, N);
}

// batched 1152x1152 transpose-convert: z selects (src, dst) pair
__global__ __launch_bounds__(256) void k_tcvt4(const float* __restrict__ s0, u16* __restrict__ d0,
                                               const float* __restrict__ s1, u16* __restrict__ d1,
                                               const float* __restrict__ s2, u16* __restrict__ d2,
                                               const float* __restrict__ s3, u16* __restrict__ d3) {
  const float* in;
  u16* out;
  switch (blockIdx.z) {
    case 0: in = s0; out = d0; break;
    case 1: in = s1; out = d1; break;
    case 2: in = s2; out = d2; break;
    default: in = s3; out = d3; break;
  }
  tcvt_body(in, out, 1152, 1152);
}

// ------- fused LayerNorm + modulate -> bf16 row -------
__global__ __launch_bounds__(256) void k_lnmod(const float* __restrict__ xin,
                                               const float* __restrict__ w,
                                               const float* __restrict__ bs,
                                               const float* __restrict__ mo,
                                               int sh_off, int sc_off, u16* __restrict__ o) {
  int row = blockIdx.x;
  int b = row >> 10;
  int tid = threadIdx.x;
  const float4* x4 = (const float4*)(xin + (size_t)row * 1152);
  float4 v0 = x4[tid];
  float4 v1 = make_float4(0.f, 0.f, 0.f, 0.f);
  if (tid < 32) v1 = x4[256 + tid];
  float s = v0.x + v0.y + v0.z + v0.w + v1.x + v1.y + v1.z + v1.w;
  float sq = v0.x * v0.x + v0.y * v0.y + v0.z * v0.z + v0.w * v0.w +
             v1.x * v1.x + v1.y * v1.y + v1.z * v1.z + v1.w * v1.w;
  #pragma unroll
  for (int d = 32; d > 0; d >>= 1) { s += __shfl_down(s, d); sq += __shfl_down(sq, d); }
  __shared__ float ps[4], pq[4];
  int wid = tid >> 6, lane = tid & 63;
  if (lane == 0) { ps[wid] = s; pq[wid] = sq; }
  __syncthreads();
  float S = ps[0] + ps[1] + ps[2] + ps[3];
  float SQ = pq[0] + pq[1] + pq[2] + pq[3];
  float mean = S * (1.f / 1152.f);
  float var = SQ * (1.f / 1152.f) - mean * mean;
  float rs = rsqrtf(var + 1e-5f);
  const float* shp = mo + (size_t)b * 6912 + sh_off;
  const float* scp = mo + (size_t)b * 6912 + sc_off;
  u16* orow = o + (size_t)row * 1152;
  {
    int col = 4 * tid;
    ushort4 u; float y;
    y = (v0.x - mean) * rs * w[col + 0] + bs[col + 0]; u.x = f2bf(y * (1.f + scp[col + 0]) + shp[col + 0]);
    y = (v0.y - mean) * rs * w[col + 1] + bs[col + 1]; u.y = f2bf(y * (1.f + scp[col + 1]) + shp[col + 1]);
    y = (v0.z - mean) * rs * w[col + 2] + bs[col + 2]; u.z = f2bf(y * (1.f + scp[col + 2]) + shp[col + 2]);
    y = (v0.w - mean) * rs * w[col + 3] + bs[col + 3]; u.w = f2bf(y * (1.f + scp[col + 3]) + shp[col + 3]);
    *(ushort4*)&orow[col] = u;
  }
  if (tid < 32) {
    int col = 1024 + 4 * tid;
    ushort4 u; float y;
    y = (v1.x - mean) * rs * w[col + 0] + bs[col + 0]; u.x = f2bf(y * (1.f + scp[col + 0]) + shp[col + 0]);
    y = (v1.y - mean) * rs * w[col + 1] + bs[col + 1]; u.y = f2bf(y * (1.f + scp[col + 1]) + shp[col + 1]);
    y = (v1.z - mean) * rs * w[col + 2] + bs[col + 2]; u.z = f2bf(y * (1.f + scp[col + 2]) + shp[col + 2]);
    y = (v1.w - mean) * rs * w[col + 3] + bs[col + 3]; u.w = f2bf(y * (1.f + scp[col + 3]) + shp[col + 3]);
    *(ushort4*)&orow[col] = u;
  }
}

// ======= 4-PHASE GEMM (r17): BM=BN=256, 512 thr, BK=64 =======
// klen multiple of 128. Phase = {VM(8); bar; 12 deduped reads; stage; setprio;
// 16 MFMA32 (compiler-inserted fine-grained lgkm waits)}.
// EPI 2: gelu, stride gridDim.x*256 (fc1)
// EPI 3: QKV (Q,K stride 3456; V transposed to vt)
// EPI 5: bf16 partial, stride 1152, guard gcol<1152, z-offset (fc2 split-K)
template <int EPI>
__global__ __launch_bounds__(512, 2) void k_gemm8p(const u16* __restrict__ A,
                                                   const u16* __restrict__ Bt,
                                                   int Kst, int klen,
                                                   u16* __restrict__ Cb,
                                                   const float* __restrict__ bias,
                                                   u16* __restrict__ vt) {
  const int tid = threadIdx.x;
  const int w = tid >> 6, lane = tid & 63;
  const int wm = w >> 2, wn = w & 3;
  const int l31 = lane & 31, hi = lane >> 5;

  const int nwg = gridDim.x * gridDim.y;
  const int id = blockIdx.y * gridDim.x + blockIdx.x;
  const int swz = (id & 7) * (nwg >> 3) + (id >> 3);
  const int tM = (swz / gridDim.x) * 256, tN = (swz % gridDim.x) * 256;
  const int koff = blockIdx.z * klen;

  __shared__ u16 lA[2][2][256 * 32];
  __shared__ u16 lB[2][2][256 * 32];
  f32x16 acc[4][2];
  #pragma unroll
  for (int m = 0; m < 4; ++m)
    #pragma unroll
    for (int n = 0; n < 2; ++n)
      #pragma unroll
      for (int r = 0; r < 16; ++r) acc[m][n][r] = 0.f;

  const int lrow = lane >> 2, lseg = lane & 3;
  const int fl = (lrow & 3) ^ ((lrow >> 2) & 3);
  const u16* gA = A + (size_t)(tM + w * 32 + lrow) * Kst + (lseg ^ fl) * 8 + koff;
  const u16* gB = Bt + (size_t)(tN + w * 32 + lrow) * Kst + (lseg ^ fl) * 8 + koff;
  const size_t rstep = (size_t)16 * Kst;
  const int wo0 = (w * 32) * 32, wo1 = (w * 32 + 16) * 32;
  const int fr = (l31 & 3) ^ ((l31 >> 2) & 3);
  const int c0 = (hi ^ fr) * 8;
  const int c1 = ((hi ^ fr) ^ 2) * 8;
  const int arow = (wm * 128 + l31) * 32;
  const int brow = (wn * 64 + l31) * 32;

#define SA(BUF, KH, KO)                                       \
  do {                                                        \
    gload16(gA + (KO), &lA[BUF][KH][wo0]);                    \
    gload16(gA + rstep + (KO), &lA[BUF][KH][wo1]);            \
  } while (0)
#define SB(BUF, KH, KO)                                       \
  do {                                                        \
    gload16(gB + (KO), &lB[BUF][KH][wo0]);                    \
    gload16(gB + rstep + (KO), &lB[BUF][KH][wo1]);            \
  } while (0)
#define VM(Nst) asm volatile("s_waitcnt vmcnt(" #Nst ")" ::: "memory")

#define PHASE(CB, KH, STAGE_STMT)                                               \
  do {                                                                          \
    __builtin_amdgcn_s_barrier();                                               \
    __builtin_amdgcn_sched_barrier(0);                                          \
    bf16x8 af[4][2], bf[2][2];                                                  \
    _Pragma("unroll")                                                           \
    for (int m_ = 0; m_ < 4; ++m_) {                                            \
      af[m_][0] = *(const bf16x8*)&lA[CB][KH][arow + m_ * 1024 + c0];           \
      af[m_][1] = *(const bf16x8*)&lA[CB][KH][arow + m_ * 1024 + c1];           \
    }                                                                           \
    _Pragma("unroll")                                                           \
    for (int n_ = 0; n_ < 2; ++n_) {                                            \
      bf[n_][0] = *(const bf16x8*)&lB[CB][KH][brow + n_ * 1024 + c0];           \
      bf[n_][1] = *(const bf16x8*)&lB[CB][KH][brow + n_ * 1024 + c1];           \
    }                                                                           \
    STAGE_STMT;                                                                 \
    __builtin_amdgcn_s_setprio(1);                                              \
    _Pragma("unroll")                                                           \
    for (int m_ = 0; m_ < 4; ++m_)                                              \
      _Pragma("unroll")                                                         \
      for (int n_ = 0; n_ < 2; ++n_)                                            \
        acc[m_][n_] = MFMA32(af[m_][0], bf[n_][0], acc[m_][n_]);                \
    _Pragma("unroll")                                                           \
    for (int m_ = 0; m_ < 4; ++m_)                                              \
      _Pragma("unroll")                                                         \
      for (int n_ = 0; n_ < 2; ++n_)                                            \
        acc[m_][n_] = MFMA32(af[m_][1], bf[n_][1], acc[m_][n_]);                \
    __builtin_amdgcn_s_setprio(0);                                              \
  } while (0)

  const int NIT = klen >> 7;
  SA(0, 0, 0); SB(0, 0, 0);
  SA(0, 1, 32); SB(0, 1, 32);
  SA(1, 0, 64); SB(1, 0, 64);
  for (int it = 0; it < NIT - 1; ++it) {
    const int kb = it * 128;
    VM(8); PHASE(0, 0, { SA(1, 1, kb + 96);  SB(1, 1, kb + 96);  });
    VM(8); PHASE(0, 1, { SA(0, 0, kb + 128); SB(0, 0, kb + 128); });
    VM(8); PHASE(1, 0, { SA(0, 1, kb + 160); SB(0, 1, kb + 160); });
    VM(8); PHASE(1, 1, { SA(1, 0, kb + 192); SB(1, 0, kb + 192); });
  }
  {
    const int kb = (NIT - 1) * 128;
    VM(8); PHASE(0, 0, { SA(1, 1, kb + 96); SB(1, 1, kb + 96); });
    VM(8); PHASE(0, 1, (void)0);
    VM(4); PHASE(1, 0, (void)0);
    VM(0); PHASE(1, 1, (void)0);
  }
#undef SA
#undef SB
#undef VM
#undef PHASE

  // epilogue: 32x32 D layout: col = lane&31, row = (reg&3) + 8*(reg>>2) + 4*(lane>>5)
  #pragma unroll
  for (int m = 0; m < 4; ++m)
    #pragma unroll
    for (int n = 0; n < 2; ++n) {
      int gcol = tN + wn * 64 + n * 32 + l31;
      #pragma unroll
      for (int q = 0; q < 4; ++q) {
        int grow0 = tM + wm * 128 + m * 32 + hi * 4 + q * 8;
        if (EPI == 3) {
          if (gcol < 2304) {
            #pragma unroll
            for (int r = 0; r < 4; ++r)
              Cb[(size_t)(grow0 + r) * 3456 + gcol] = f2bf(acc[m][n][q * 4 + r]);
          } else if (gcol < 3456) {
            int qq = gcol - 2304;
            int hh = qq / 72;
            int d = qq - hh * 72;
            int bb = grow0 >> 10, sl = grow0 & 1023;
            ushort4 u;
            u.x = f2bf(acc[m][n][q * 4 + 0]); u.y = f2bf(acc[m][n][q * 4 + 1]);
            u.z = f2bf(acc[m][n][q * 4 + 2]); u.w = f2bf(acc[m][n][q * 4 + 3]);
            *(ushort4*)&vt[(((size_t)bb * 16 + hh) * 72 + d) * 1024 + sl] = u;
          }
        } else if (EPI == 5) {
          if (gcol < 1152) {
            u16* Po = Cb + (size_t)blockIdx.z * 9437184ull;  // 8192*1152
            #pragma unroll
            for (int r = 0; r < 4; ++r)
              Po[(size_t)(grow0 + r) * 1152 + gcol] = f2bf(acc[m][n][q * 4 + r]);
          }
        } else {  // EPI 2: fast gelu
          const int NC = gridDim.x * 256;
          float bi = bias[gcol];
          #pragma unroll
          for (int r = 0; r < 4; ++r) {
            float z = acc[m][n][q * 4 + r] + bi;
            float z2 = z * z;
            float u = z * __fmaf_rn(z2, -0.0713548162f, -1.5957691216f);
            float e = __expf(u);
            Cb[(size_t)(grow0 + r) * NC + gcol] = f2bf(z * __builtin_amdgcn_rcpf(1.f + e));
          }
        }
      }
    }
}

// ------- 128x128 4-wave GEMM (r11, for wo): 32x32 frags, depth-3 counted-vmcnt -------
template <int EPI>
__global__ __launch_bounds__(256) void k_gemm(const u16* __restrict__ A, const u16* __restrict__ Bt,
                                              int Kst, int klen, u16* __restrict__ Cb,
                                              float* __restrict__ Cf,
                                              const float* __restrict__ bias,
                                              const float* __restrict__ res,
                                              const float* __restrict__ mo, int goff,
                                              u16* __restrict__ vt) {
  const int tid = threadIdx.x;
  const int w = tid >> 6, lane = tid & 63;
  const int wr = w >> 1, wc = w & 1;
  const int l31 = lane & 31, hi = lane >> 5;

  const int nwg = gridDim.x * gridDim.y;
  const int id = blockIdx.y * gridDim.x + blockIdx.x;
  const int swz = (id & 7) * (nwg >> 3) + (id >> 3);
  const int tM = (swz / gridDim.x) * 128, tN = (swz % gridDim.x) * 128;
  const int N = gridDim.x * 128;
  const int koff = blockIdx.z * klen;

  __shared__ u16 lA[3][128 * 32];
  __shared__ u16 lB[3][128 * 32];
  f32x16 acc[2][2];
  #pragma unroll
  for (int m = 0; m < 2; ++m)
    #pragma unroll
    for (int n = 0; n < 2; ++n)
      #pragma unroll
      for (int r = 0; r < 16; ++r) acc[m][n][r] = 0.f;

  const int lrow = lane >> 2, lseg = lane & 3;
  const int fl = (lrow & 3) ^ ((lrow >> 2) & 3);
  const u16* gA = A + (size_t)(tM + w * 32 + lrow) * Kst + (lseg ^ fl) * 8 + koff;
  const u16* gB = Bt + (size_t)(tN + w * 32 + lrow) * Kst + (lseg ^ fl) * 8 + koff;
  const size_t rstep = (size_t)16 * Kst;
  const int wo0 = (w * 32) * 32, wo1 = (w * 32 + 16) * 32;
  const int fr = (l31 & 3) ^ ((l31 >> 2) & 3);
  const int c0 = (hi ^ fr) * 8;
  const int c1 = ((hi ^ fr) ^ 2) * 8;
  const int arow = (wr * 64 + l31) * 32;
  const int brow = (wc * 64 + l31) * 32;

#define STAGE(buf, ks)                        \
  do {                                        \
    gload16(gA + (ks), lA[buf] + wo0);        \
    gload16(gA + rstep + (ks), lA[buf] + wo1);\
    gload16(gB + (ks), lB[buf] + wo0);        \
    gload16(gB + rstep + (ks), lB[buf] + wo1);\
  } while (0)

#define COMPUTE(buf)                                                            \
  do {                                                                          \
    bf16x8 a00 = *(const bf16x8*)&lA[buf][arow + c0];                           \
    bf16x8 a01 = *(const bf16x8*)&lA[buf][arow + c1];                           \
    bf16x8 a10 = *(const bf16x8*)&lA[buf][arow + 1024 + c0];                    \
    bf16x8 a11 = *(const bf16x8*)&lA[buf][arow + 1024 + c1];                    \
    bf16x8 b00 = *(const bf16x8*)&lB[buf][brow + c0];                           \
    bf16x8 b01 = *(const bf16x8*)&lB[buf][brow + c1];                           \
    bf16x8 b10 = *(const bf16x8*)&lB[buf][brow + 1024 + c0];                    \
    bf16x8 b11 = *(const bf16x8*)&lB[buf][brow + 1024 + c1];                    \
    __builtin_amdgcn_s_setprio(1);                                              \
    acc[0][0] = MFMA32(a00, b00, acc[0][0]);                                    \
    acc[0][1] = MFMA32(a00, b10, acc[0][1]);                                    \
    acc[1][0] = MFMA32(a10, b00, acc[1][0]);                                    \
    acc[1][1] = MFMA32(a10, b10, acc[1][1]);                                    \
    acc[0][0] = MFMA32(a01, b01, acc[0][0]);                                    \
    acc[0][1] = MFMA32(a01, b11, acc[0][1]);                                    \
    acc[1][0] = MFMA32(a11, b01, acc[1][0]);                                    \
    acc[1][1] = MFMA32(a11, b11, acc[1][1]);                                    \
    __builtin_amdgcn_s_setprio(0);                                              \
  } while (0)

#define WAITBAR(Nst)                                          \
  do {                                                        \
    asm volatile("s_waitcnt vmcnt(" #Nst ")" ::: "memory");   \
    __builtin_amdgcn_s_barrier();                             \
    __builtin_amdgcn_sched_barrier(0);                        \
  } while (0)

  const int nt = klen >> 5;
  STAGE(0, 0);
  STAGE(1, 32);
  int ks = 64;
  for (int g = 0; g < nt / 3 - 1; ++g) {
    WAITBAR(4); STAGE(2, ks);      COMPUTE(0);
    WAITBAR(4); STAGE(0, ks + 32); COMPUTE(1);
    WAITBAR(4); STAGE(1, ks + 64); COMPUTE(2);
    ks += 96;
  }
  WAITBAR(4); STAGE(2, ks); COMPUTE(0);
  WAITBAR(4); COMPUTE(1);
  WAITBAR(0); COMPUTE(2);
#undef STAGE
#undef COMPUTE
#undef WAITBAR

  #pragma unroll
  for (int m = 0; m < 2; ++m)
    #pragma unroll
    for (int n = 0; n < 2; ++n) {
      int gcol = tN + wc * 64 + n * 32 + l31;
      #pragma unroll
      for (int q = 0; q < 4; ++q) {
        int grow0 = tM + wr * 64 + m * 32 + hi * 4 + q * 8;
        float g = mo[(size_t)(grow0 >> 10) * 6912 + goff + gcol];
        float bi = bias[gcol];
        #pragma unroll
        for (int r = 0; r < 4; ++r) {
          size_t idx = (size_t)(grow0 + r) * N + gcol;
          Cf[idx] = res[idx] + g * (acc[m][n][q * 4 + r] + bi);
        }
      }
    }
}

// ------- fc2 split-K x3 reduce (grid-stride, 4 float4/thread) -------
__global__ __launch_bounds__(256) void k_fc2red(const u16* __restrict__ p,
                                                const float* __restrict__ x1,
                                                const float* __restrict__ bias,
                                                const float* __restrict__ mo,
                                                float* __restrict__ out) {
  #pragma unroll
  for (int it = 0; it < 4; ++it) {
    size_t idx4 = (size_t)(blockIdx.x * 4 + it) * 256 + threadIdx.x;
    size_t i = idx4 * 4;  // over 8192*1152
    int row = (int)(i / 1152);
    int col = (int)(i - (size_t)row * 1152);
    int b = row >> 10;
    ushort4 a0 = *(const ushort4*)(p + i);
    ushort4 a1 = *(const ushort4*)(p + 9437184ull + i);
    ushort4 a2 = *(const ushort4*)(p + 18874368ull + i);
    float4 r = *(const float4*)(x1 + i);
    const float* gp = mo + (size_t)b * 6912 + 5760 + col;
    const float* bp = bias + col;
    float4 o;
    o.x = r.x + gp[0] * (bf2f(a0.x) + bf2f(a1.x) + bf2f(a2.x) + bp[0]);
    o.y = r.y + gp[1] * (bf2f(a0.y) + bf2f(a1.y) + bf2f(a2.y) + bp[1]);
    o.z = r.z + gp[2] * (bf2f(a0.z) + bf2f(a1.z) + bf2f(a2.z) + bp[2]);
    o.w = r.w + gp[3] * (bf2f(a0.w) + bf2f(a1.w) + bf2f(a2.w) + bp[3]);
    *(float4*)(out + i) = o;
  }
}

// ------- flash attention, swapped-QK^T structure -------
__global__ __launch_bounds__(256) void k_attn(const u16* __restrict__ QKV, const u16* __restrict__ Vt,
                                              u16* __restrict__ O) {
  const int tid = threadIdx.x;
  const int w = tid >> 6, lane = tid & 63;
  const int lr = lane & 15, kg = lane >> 4;
  int bx = blockIdx.x;
  bx = (bx & 7) * 256 + (bx >> 3);
  const int qt = bx & 15, h = (bx >> 4) & 15, b = bx >> 8;

  __shared__ u16 lQ[64][104];
  __shared__ u16 lK[64][104];
  __shared__ u16 lVt[80][72];
  __shared__ u16 lPt[4][16][72];

  const size_t qkbase = (size_t)b * 1024 * 3456 + (size_t)h * 72;
  const u16* Qg = QKV + qkbase;
  const u16* Kg = QKV + qkbase + 1152;
  const u16* Vg = Vt + ((size_t)(b * 16 + h) * 72) * 1024;

  const uint4 z4 = make_uint4(0, 0, 0, 0);
  for (int L = tid; L < 192; L += 256) {
    int r = L / 3, s = L - (L / 3) * 3;
    *(uint4*)&lQ[r][72 + s * 8] = z4;
    *(uint4*)&lK[r][72 + s * 8] = z4;
  }
  for (int L = tid; L < 72; L += 256) {
    int r = L / 9, s = L - (L / 9) * 9;
    *(uint4*)&lVt[72 + r][s * 8] = z4;
  }
  {
    int L = tid; int r = L / 9, s = L - r * 9;
    *(uint4*)&lQ[r][s * 8] = *(const uint4*)(Qg + (size_t)(qt * 64 + r) * 3456 + s * 8);
    L = tid + 256; r = L / 9; s = L - r * 9;
    *(uint4*)&lQ[r][s * 8] = *(const uint4*)(Qg + (size_t)(qt * 64 + r) * 3456 + s * 8);
    if (tid < 64) {
      L = tid + 512; r = L / 9; s = L - r * 9;
      *(uint4*)&lQ[r][s * 8] = *(const uint4*)(Qg + (size_t)(qt * 64 + r) * 3456 + s * 8);
    }
  }
  __syncthreads();

  bf16x8 bq[3];
  #pragma unroll
  for (int ks = 0; ks < 3; ++ks) bq[ks] = *(const bf16x8*)&lQ[w * 16 + lr][ks * 32 + kg * 8];

  const float scale = 0.11785113019775793f;  // 1/sqrt(72)
  float mrun = -1e30f, lrun = 0.f;
  f32x4 oacc[5];
  #pragma unroll
  for (int nd = 0; nd < 5; ++nd) oacc[nd] = f32x4{0.f, 0.f, 0.f, 0.f};

  for (int kt = 0; kt < 16; ++kt) {
    __syncthreads();
    {
      int L = tid; int r = L / 9, s = L - (L / 9) * 9;
      *(uint4*)&lK[r][s * 8] = *(const uint4*)(Kg + (size_t)(kt * 64 + r) * 3456 + s * 8);
      int d = tid >> 3, sg = tid & 7;
      *(uint4*)&lVt[d][sg * 8] = *(const uint4*)(Vg + (size_t)d * 1024 + kt * 64 + sg * 8);
      L = tid + 256; r = L / 9; s = L - r * 9;
      *(uint4*)&lK[r][s * 8] = *(const uint4*)(Kg + (size_t)(kt * 64 + r) * 3456 + s * 8);
      d = (tid + 256) >> 3; sg = tid & 7;
      *(uint4*)&lVt[d][sg * 8] = *(const uint4*)(Vg + (size_t)d * 1024 + kt * 64 + sg * 8);
      if (tid < 64) {
        L = tid + 512; r = L / 9; s = L - r * 9;
        *(uint4*)&lK[r][s * 8] = *(const uint4*)(Kg + (size_t)(kt * 64 + r) * 3456 + s * 8);
        d = (tid + 512) >> 3;
        *(uint4*)&lVt[d][sg * 8] = *(const uint4*)(Vg + (size_t)d * 1024 + kt * 64 + sg * 8);
      }
    }
    __syncthreads();

    f32x4 sfr[4];
    __builtin_amdgcn_s_setprio(1);
    #pragma unroll
    for (int kb = 0; kb < 4; ++kb) {
      f32x4 sv = f32x4{0.f, 0.f, 0.f, 0.f};
      #pragma unroll
      for (int ks = 0; ks < 3; ++ks) {
        bf16x8 ak = *(const bf16x8*)&lK[kb * 16 + lr][ks * 32 + kg * 8];
        sv = MFMA16(ak, bq[ks], sv);
      }
      sfr[kb] = sv;
    }
    __builtin_amdgcn_s_setprio(0);

    float mx = sfr[0][0];
    #pragma unroll
    for (int kb = 0; kb < 4; ++kb)
      #pragma unroll
      for (int r = 0; r < 4; ++r) mx = fmaxf(mx, sfr[kb][r]);
    mx = fmaxf(mx, __shfl_xor(mx, 16));
    mx = fmaxf(mx, __shfl_xor(mx, 32));
    mx *= scale;
    float mn = fmaxf(mrun, mx);
    float al = __expf(mrun - mn);
    mrun = mn;
    float sum = 0.f;
    #pragma unroll
    for (int kb = 0; kb < 4; ++kb) {
      #pragma unroll
      for (int rp = 0; rp < 2; ++rp) {
        float p0 = __expf(__fmaf_rn(sfr[kb][2 * rp], scale, -mn));
        float p1 = __expf(__fmaf_rn(sfr[kb][2 * rp + 1], scale, -mn));
        sum += p0 + p1;
        u32 pk = (u32)f2bf(p0) | ((u32)f2bf(p1) << 16);
        *(u32*)&lPt[w][lr][kb * 16 + kg * 4 + rp * 2] = pk;
      }
    }
    sum += __shfl_xor(sum, 16);
    sum += __shfl_xor(sum, 32);
    lrun = lrun * al + sum;
    #pragma unroll
    for (int nd = 0; nd < 5; ++nd)
      #pragma unroll
      for (int r = 0; r < 4; ++r) oacc[nd][r] *= al;

    __builtin_amdgcn_s_setprio(1);
    #pragma unroll
    for (int s = 0; s < 2; ++s) {
      bf16x8 bp = *(const bf16x8*)&lPt[w][lr][s * 32 + kg * 8];
      #pragma unroll
      for (int nd = 0; nd < 5; ++nd) {
        bf16x8 av = *(const bf16x8*)&lVt[nd * 16 + lr][s * 32 + kg * 8];
        oacc[nd] = MFMA16(av, bp, oacc[nd]);
      }
    }
    __builtin_amdgcn_s_setprio(0);
  }

  float inv = 1.f / lrun;
  size_t orow = ((size_t)b * 1024 + qt * 64 + w * 16 + lr) * 1152 + h * 72;
  #pragma unroll
  for (int nd = 0; nd < 5; ++nd) {
    int d0 = nd * 16 + kg * 4;
    if (d0 < 72) {
      ushort4 u;
      u.x = f2bf(oacc[nd][0] * inv);
      u.y = f2bf(oacc[nd][1] * inv);
      u.z = f2bf(oacc[nd][2] * inv);
      u.w = f2bf(oacc[nd][3] * inv);
      *(ushort4*)&O[orow + d0] = u;
    }
  }
}

extern "C" void kernel_launch(void* const* d_in, const int* in_sizes, int n_in,
                              void* d_out, int out_size, void* d_ws, size_t ws_size,
                              hipStream_t stream) {
  const float* x     = (const float*)d_in[0];
  const float* c     = (const float*)d_in[1];
  const float* ln1_w = (const float*)d_in[2];
  const float* ln1_b = (const float*)d_in[3];
  const float* wq    = (const float*)d_in[4];
  const float* wk    = (const float*)d_in[5];
  const float* wv    = (const float*)d_in[6];
  const float* wo    = (const float*)d_in[7];
  const float* wo_b  = (const float*)d_in[8];
  const float* ln2_w = (const float*)d_in[9];
  const float* ln2_b = (const float*)d_in[10];
  const float* fc1_w = (const float*)d_in[11];
  const float* fc1_b = (const float*)d_in[12];
  const float* fc2_w = (const float*)d_in[13];
  const float* fc2_b = (const float*)d_in[14];
  const float* ada_w = (const float*)d_in[15];
  const float* ada_b = (const float*)d_in[16];
  float* out = (float*)d_out;

  char* base = (char*)d_ws;
  size_t off = 0;
  auto alloc = [&](size_t nbytes) -> void* {
    void* p = base + off;
    off += (nbytes + 255) & ~(size_t)255;
    return p;
  };
  const size_t MD = 8192ull * 1152;
  float* partial = (float*)alloc(64ull * 6912 * 4);
  float* modb   = (float*)alloc(55296 * 4);
  u16* qkvT = (u16*)alloc(3584ull * 1152 * 2);   // padded to 3584 rows
  u16* woT  = (u16*)alloc(1152ull * 1152 * 2);
  u16* fc1T = (u16*)alloc(4608ull * 1152 * 2);
  u16* fc2T = (u16*)alloc(1280ull * 4608 * 2);   // padded to 1280 rows
  u16* hbuf = (u16*)alloc(MD * 2);               // h -> attnO -> h2
  float* x1 = (float*)alloc(MD * 4);
  u16* vtb  = (u16*)alloc(128ull * 72 * 1024 * 2);
  u16* fc2p = (u16*)alloc(3ull * MD * 2);        // bf16 partials x3, stride 1152
  u16* big  = (u16*)alloc(8192ull * 4608 * 2);   // qkv (stride 3456) then m1
  u16* qkv = big;
  u16* m1 = big;
  // total ws ~243 MB (fits 256 MiB = 268.4 MB)

  k_modproj1<<<dim3(27, 8), 256, 0, stream>>>(c, ada_w, partial);
  k_modproj2<<<27, 256, 0, stream>>>(partial, ada_b, modb);
  // batched: wq,wk,wv,wo in a single launch (z=0..3)
  k_tcvt4<<<dim3(36, 36, 4), 256, 0, stream>>>(
      wq, qkvT, wk, qkvT + 1152ull * 1152, wv, qkvT + 2304ull * 1152, wo, woT);
  k_tcvt<<<dim3(144, 36), 256, 0, stream>>>(fc1_w, fc1T, 1152, 4608);
  k_tcvt<<<dim3(36, 144), 256, 0, stream>>>(fc2_w, fc2T, 4608, 1152);

  // h = modulate(LN(x), sh_msa, sc_msa)
  k_lnmod<<<8192, 256, 0, stream>>>(x, ln1_w, ln1_b, modb, 0, 1152, hbuf);
  // qkv (4-phase): Q,K rows into qkv (stride 3456), V transposed into vtb
  k_gemm8p<3><<<dim3(14, 32), 512, 0, stream>>>(hbuf, qkvT, 1152, 1152, qkv, nullptr, vtb);
  // attention -> O (reuse hbuf)
  k_attn<<<2048, 256, 0, stream>>>(qkv, vtb, hbuf);
  // x1 = x + g_msa*(O@wo + wo_b)   (4-wave)
  k_gemm<1><<<dim3(9, 64), 256, 0, stream>>>(hbuf, woT, 1152, 1152, nullptr, x1, wo_b, x, modb, 2304, nullptr);
  // h2 = modulate(LN(x1), sh_mlp, sc_mlp)
  k_lnmod<<<8192, 256, 0, stream>>>(x1, ln2_w, ln2_b, modb, 3456, 4608, hbuf);
  // m1 = gelu(h2@fc1 + fc1_b)  (4-phase)
  k_gemm8p<2><<<dim3(18, 32), 512, 0, stream>>>(hbuf, fc1T, 1152, 1152, m1, fc1_b, nullptr);
  // fc2 split-K x3 (4-phase, klen=1536, 480 blocks) then fused reduce
  k_gemm8p<5><<<dim3(5, 32, 3), 512, 0, stream>>>(m1, fc2T, 4608, 1536, fc2p, nullptr, nullptr);
  k_fc2red<<<2304, 256, 0, stream>>>(fc2p, x1, fc2_b, modb, out);
}

// Round 19
// 523.183 us; speedup vs baseline: 1.0516x; 1.0211x over previous
//
#include <hip/hip_runtime.h>
#include <hip/hip_bf16.h>

// DiT block: B=8, S=1024, D=1152, H=16, HD=72, HID=4608
// k_gemm8p (r17 best): 256x256, 8 waves, 4-phase deduped-read schedule
//   {vmcnt(8); bar; 12 ds_read; stage; setprio; 16 MFMA32 (compiler lgkm)}.
//   BK=64, LDS 128KB, XOR swizzle. qkv (EPI3), fc1 (EPI2), fc2 split-K x3 (EPI5).
// k_gemm: 128^2 4-wave depth-3 counted (r11) for wo (EPI1).
// Attention: swapped QK^T, pre-transposed V, in-lane softmax,
//   r19: T14 async-STAGE split (issue K/V loads for kt+1 before kt's compute,
//   LDS-write after the post-compute barrier).

typedef unsigned short u16;
typedef unsigned int u32;
typedef __attribute__((ext_vector_type(8))) short bf16x8;
typedef __attribute__((ext_vector_type(4))) float f32x4;
typedef __attribute__((ext_vector_type(16))) float f32x16;

#define MFMA16(a, b, c) __builtin_amdgcn_mfma_f32_16x16x32_bf16((a), (b), (c), 0, 0, 0)
#define MFMA32(a, b, c) __builtin_amdgcn_mfma_f32_32x32x16_bf16((a), (b), (c), 0, 0, 0)

__device__ __forceinline__ u16 f2bf(float f) {
  __hip_bfloat16 h = __float2bfloat16(f);
  return __builtin_bit_cast(u16, h);
}

__device__ __forceinline__ float bf2f(u16 u) {
  u32 v = ((u32)u) << 16;
  return __builtin_bit_cast(float, v);
}

__device__ __forceinline__ void gload16(const u16* g, u16* l) {
  __builtin_amdgcn_global_load_lds(
      (const __attribute__((address_space(1))) unsigned int*)(const void*)g,
      (__attribute__((address_space(3))) unsigned int*)(void*)l, 16, 0, 0);
}

// ------- mod projection, split-K stage 1 (silu fused) -------
__global__ __launch_bounds__(256) void k_modproj1(const float* __restrict__ cc,
                                                  const float* __restrict__ aw,
                                                  float* __restrict__ partial) {
  __shared__ float lc[8][144];
  int kc = blockIdx.y;
  for (int i = threadIdx.x; i < 1152; i += 256) {
    int b = i / 144, k = i % 144;
    float v = cc[b * 1152 + kc * 144 + k];
    lc[b][k] = v / (1.f + __expf(-v));
  }
  __syncthreads();
  int j = blockIdx.x * 256 + threadIdx.x;
  float acc[8] = {0, 0, 0, 0, 0, 0, 0, 0};
  for (int k = 0; k < 144; ++k) {
    float w = aw[(size_t)(kc * 144 + k) * 6912 + j];
    #pragma unroll
    for (int b = 0; b < 8; ++b) acc[b] += lc[b][k] * w;
  }
  #pragma unroll
  for (int b = 0; b < 8; ++b) partial[((size_t)kc * 8 + b) * 6912 + j] = acc[b];
}

// ------- mod projection stage 2 -------
__global__ __launch_bounds__(256) void k_modproj2(const float* __restrict__ partial,
                                                  const float* __restrict__ ab,
                                                  float* __restrict__ mo) {
  int j = blockIdx.x * 256 + threadIdx.x;
  float bias = ab[j];
  #pragma unroll
  for (int b = 0; b < 8; ++b) {
    float s = 0.f;
    #pragma unroll
    for (int kc = 0; kc < 8; ++kc) s += partial[((size_t)kc * 8 + b) * 6912 + j];
    mo[(size_t)b * 6912 + j] = s + bias;
  }
}

// ------- transpose-convert: in[K][N] f32 -> out[N][K] bf16 -------
__device__ __forceinline__ void tcvt_body(const float* __restrict__ in, u16* __restrict__ out,
                                          int K, int N) {
  __shared__ float t[32][33];
  int tx = threadIdx.x & 31, ty = threadIdx.x >> 5;
  size_t bx = (size_t)blockIdx.x * 32, by = (size_t)blockIdx.y * 32;
  #pragma unroll
  for (int i = 0; i < 4; ++i) t[ty + 8 * i][tx] = in[(by + ty + 8 * i) * N + bx + tx];
  __syncthreads();
  #pragma unroll
  for (int i = 0; i < 4; ++i) out[(bx + ty + 8 * i) * K + by + tx] = f2bf(t[tx][ty + 8 * i]);
}

__global__ __launch_bounds__(256) void k_tcvt(const float* __restrict__ in, u16* __restrict__ out,
                                              int K, int N) {
  tcvt_body(in, out, K, N);
}

// batched 1152x1152 transpose-convert: z selects (src, dst) pair
__global__ __launch_bounds__(256) void k_tcvt4(const float* __restrict__ s0, u16* __restrict__ d0,
                                               const float* __restrict__ s1, u16* __restrict__ d1,
                                               const float* __restrict__ s2, u16* __restrict__ d2,
                                               const float* __restrict__ s3, u16* __restrict__ d3) {
  const float* in;
  u16* out;
  switch (blockIdx.z) {
    case 0: in = s0; out = d0; break;
    case 1: in = s1; out = d1; break;
    case 2: in = s2; out = d2; break;
    default: in = s3; out = d3; break;
  }
  tcvt_body(in, out, 1152, 1152);
}

// ------- fused LayerNorm + modulate -> bf16 row -------
__global__ __launch_bounds__(256) void k_lnmod(const float* __restrict__ xin,
                                               const float* __restrict__ w,
                                               const float* __restrict__ bs,
                                               const float* __restrict__ mo,
                                               int sh_off, int sc_off, u16* __restrict__ o) {
  int row = blockIdx.x;
  int b = row >> 10;
  int tid = threadIdx.x;
  const float4* x4 = (const float4*)(xin + (size_t)row * 1152);
  float4 v0 = x4[tid];
  float4 v1 = make_float4(0.f, 0.f, 0.f, 0.f);
  if (tid < 32) v1 = x4[256 + tid];
  float s = v0.x + v0.y + v0.z + v0.w + v1.x + v1.y + v1.z + v1.w;
  float sq = v0.x * v0.x + v0.y * v0.y + v0.z * v0.z + v0.w * v0.w +
             v1.x * v1.x + v1.y * v1.y + v1.z * v1.z + v1.w * v1.w;
  #pragma unroll
  for (int d = 32; d > 0; d >>= 1) { s += __shfl_down(s, d); sq += __shfl_down(sq, d); }
  __shared__ float ps[4], pq[4];
  int wid = tid >> 6, lane = tid & 63;
  if (lane == 0) { ps[wid] = s; pq[wid] = sq; }
  __syncthreads();
  float S = ps[0] + ps[1] + ps[2] + ps[3];
  float SQ = pq[0] + pq[1] + pq[2] + pq[3];
  float mean = S * (1.f / 1152.f);
  float var = SQ * (1.f / 1152.f) - mean * mean;
  float rs = rsqrtf(var + 1e-5f);
  const float* shp = mo + (size_t)b * 6912 + sh_off;
  const float* scp = mo + (size_t)b * 6912 + sc_off;
  u16* orow = o + (size_t)row * 1152;
  {
    int col = 4 * tid;
    ushort4 u; float y;
    y = (v0.x - mean) * rs * w[col + 0] + bs[col + 0]; u.x = f2bf(y * (1.f + scp[col + 0]) + shp[col + 0]);
    y = (v0.y - mean) * rs * w[col + 1] + bs[col + 1]; u.y = f2bf(y * (1.f + scp[col + 1]) + shp[col + 1]);
    y = (v0.z - mean) * rs * w[col + 2] + bs[col + 2]; u.z = f2bf(y * (1.f + scp[col + 2]) + shp[col + 2]);
    y = (v0.w - mean) * rs * w[col + 3] + bs[col + 3]; u.w = f2bf(y * (1.f + scp[col + 3]) + shp[col + 3]);
    *(ushort4*)&orow[col] = u;
  }
  if (tid < 32) {
    int col = 1024 + 4 * tid;
    ushort4 u; float y;
    y = (v1.x - mean) * rs * w[col + 0] + bs[col + 0]; u.x = f2bf(y * (1.f + scp[col + 0]) + shp[col + 0]);
    y = (v1.y - mean) * rs * w[col + 1] + bs[col + 1]; u.y = f2bf(y * (1.f + scp[col + 1]) + shp[col + 1]);
    y = (v1.z - mean) * rs * w[col + 2] + bs[col + 2]; u.z = f2bf(y * (1.f + scp[col + 2]) + shp[col + 2]);
    y = (v1.w - mean) * rs * w[col + 3] + bs[col + 3]; u.w = f2bf(y * (1.f + scp[col + 3]) + shp[col + 3]);
    *(ushort4*)&orow[col] = u;
  }
}

// ======= 4-PHASE GEMM (r17): BM=BN=256, 512 thr, BK=64 =======
template <int EPI>
__global__ __launch_bounds__(512, 2) void k_gemm8p(const u16* __restrict__ A,
                                                   const u16* __restrict__ Bt,
                                                   int Kst, int klen,
                                                   u16* __restrict__ Cb,
                                                   const float* __restrict__ bias,
                                                   u16* __restrict__ vt) {
  const int tid = threadIdx.x;
  const int w = tid >> 6, lane = tid & 63;
  const int wm = w >> 2, wn = w & 3;
  const int l31 = lane & 31, hi = lane >> 5;

  const int nwg = gridDim.x * gridDim.y;
  const int id = blockIdx.y * gridDim.x + blockIdx.x;
  const int swz = (id & 7) * (nwg >> 3) + (id >> 3);
  const int tM = (swz / gridDim.x) * 256, tN = (swz % gridDim.x) * 256;
  const int koff = blockIdx.z * klen;

  __shared__ u16 lA[2][2][256 * 32];
  __shared__ u16 lB[2][2][256 * 32];
  f32x16 acc[4][2];
  #pragma unroll
  for (int m = 0; m < 4; ++m)
    #pragma unroll
    for (int n = 0; n < 2; ++n)
      #pragma unroll
      for (int r = 0; r < 16; ++r) acc[m][n][r] = 0.f;

  const int lrow = lane >> 2, lseg = lane & 3;
  const int fl = (lrow & 3) ^ ((lrow >> 2) & 3);
  const u16* gA = A + (size_t)(tM + w * 32 + lrow) * Kst + (lseg ^ fl) * 8 + koff;
  const u16* gB = Bt + (size_t)(tN + w * 32 + lrow) * Kst + (lseg ^ fl) * 8 + koff;
  const size_t rstep = (size_t)16 * Kst;
  const int wo0 = (w * 32) * 32, wo1 = (w * 32 + 16) * 32;
  const int fr = (l31 & 3) ^ ((l31 >> 2) & 3);
  const int c0 = (hi ^ fr) * 8;
  const int c1 = ((hi ^ fr) ^ 2) * 8;
  const int arow = (wm * 128 + l31) * 32;
  const int brow = (wn * 64 + l31) * 32;

#define SA(BUF, KH, KO)                                       \
  do {                                                        \
    gload16(gA + (KO), &lA[BUF][KH][wo0]);                    \
    gload16(gA + rstep + (KO), &lA[BUF][KH][wo1]);            \
  } while (0)
#define SB(BUF, KH, KO)                                       \
  do {                                                        \
    gload16(gB + (KO), &lB[BUF][KH][wo0]);                    \
    gload16(gB + rstep + (KO), &lB[BUF][KH][wo1]);            \
  } while (0)
#define VM(Nst) asm volatile("s_waitcnt vmcnt(" #Nst ")" ::: "memory")

#define PHASE(CB, KH, STAGE_STMT)                                               \
  do {                                                                          \
    __builtin_amdgcn_s_barrier();                                               \
    __builtin_amdgcn_sched_barrier(0);                                          \
    bf16x8 af[4][2], bf[2][2];                                                  \
    _Pragma("unroll")                                                           \
    for (int m_ = 0; m_ < 4; ++m_) {                                            \
      af[m_][0] = *(const bf16x8*)&lA[CB][KH][arow + m_ * 1024 + c0];           \
      af[m_][1] = *(const bf16x8*)&lA[CB][KH][arow + m_ * 1024 + c1];           \
    }                                                                           \
    _Pragma("unroll")                                                           \
    for (int n_ = 0; n_ < 2; ++n_) {                                            \
      bf[n_][0] = *(const bf16x8*)&lB[CB][KH][brow + n_ * 1024 + c0];           \
      bf[n_][1] = *(const bf16x8*)&lB[CB][KH][brow + n_ * 1024 + c1];           \
    }                                                                           \
    STAGE_STMT;                                                                 \
    __builtin_amdgcn_s_setprio(1);                                              \
    _Pragma("unroll")                                                           \
    for (int m_ = 0; m_ < 4; ++m_)                                              \
      _Pragma("unroll")                                                         \
      for (int n_ = 0; n_ < 2; ++n_)                                            \
        acc[m_][n_] = MFMA32(af[m_][0], bf[n_][0], acc[m_][n_]);                \
    _Pragma("unroll")                                                           \
    for (int m_ = 0; m_ < 4; ++m_)                                              \
      _Pragma("unroll")                                                         \
      for (int n_ = 0; n_ < 2; ++n_)                                            \
        acc[m_][n_] = MFMA32(af[m_][1], bf[n_][1], acc[m_][n_]);                \
    __builtin_amdgcn_s_setprio(0);                                              \
  } while (0)

  const int NIT = klen >> 7;
  SA(0, 0, 0); SB(0, 0, 0);
  SA(0, 1, 32); SB(0, 1, 32);
  SA(1, 0, 64); SB(1, 0, 64);
  for (int it = 0; it < NIT - 1; ++it) {
    const int kb = it * 128;
    VM(8); PHASE(0, 0, { SA(1, 1, kb + 96);  SB(1, 1, kb + 96);  });
    VM(8); PHASE(0, 1, { SA(0, 0, kb + 128); SB(0, 0, kb + 128); });
    VM(8); PHASE(1, 0, { SA(0, 1, kb + 160); SB(0, 1, kb + 160); });
    VM(8); PHASE(1, 1, { SA(1, 0, kb + 192); SB(1, 0, kb + 192); });
  }
  {
    const int kb = (NIT - 1) * 128;
    VM(8); PHASE(0, 0, { SA(1, 1, kb + 96); SB(1, 1, kb + 96); });
    VM(8); PHASE(0, 1, (void)0);
    VM(4); PHASE(1, 0, (void)0);
    VM(0); PHASE(1, 1, (void)0);
  }
#undef SA
#undef SB
#undef VM
#undef PHASE

  // epilogue: 32x32 D layout: col = lane&31, row = (reg&3) + 8*(reg>>2) + 4*(lane>>5)
  #pragma unroll
  for (int m = 0; m < 4; ++m)
    #pragma unroll
    for (int n = 0; n < 2; ++n) {
      int gcol = tN + wn * 64 + n * 32 + l31;
      #pragma unroll
      for (int q = 0; q < 4; ++q) {
        int grow0 = tM + wm * 128 + m * 32 + hi * 4 + q * 8;
        if (EPI == 3) {
          if (gcol < 2304) {
            #pragma unroll
            for (int r = 0; r < 4; ++r)
              Cb[(size_t)(grow0 + r) * 3456 + gcol] = f2bf(acc[m][n][q * 4 + r]);
          } else if (gcol < 3456) {
            int qq = gcol - 2304;
            int hh = qq / 72;
            int d = qq - hh * 72;
            int bb = grow0 >> 10, sl = grow0 & 1023;
            ushort4 u;
            u.x = f2bf(acc[m][n][q * 4 + 0]); u.y = f2bf(acc[m][n][q * 4 + 1]);
            u.z = f2bf(acc[m][n][q * 4 + 2]); u.w = f2bf(acc[m][n][q * 4 + 3]);
            *(ushort4*)&vt[(((size_t)bb * 16 + hh) * 72 + d) * 1024 + sl] = u;
          }
        } else if (EPI == 5) {
          if (gcol < 1152) {
            u16* Po = Cb + (size_t)blockIdx.z * 9437184ull;  // 8192*1152
            #pragma unroll
            for (int r = 0; r < 4; ++r)
              Po[(size_t)(grow0 + r) * 1152 + gcol] = f2bf(acc[m][n][q * 4 + r]);
          }
        } else {  // EPI 2: fast gelu
          const int NC = gridDim.x * 256;
          float bi = bias[gcol];
          #pragma unroll
          for (int r = 0; r < 4; ++r) {
            float z = acc[m][n][q * 4 + r] + bi;
            float z2 = z * z;
            float u = z * __fmaf_rn(z2, -0.0713548162f, -1.5957691216f);
            float e = __expf(u);
            Cb[(size_t)(grow0 + r) * NC + gcol] = f2bf(z * __builtin_amdgcn_rcpf(1.f + e));
          }
        }
      }
    }
}

// ------- 128x128 4-wave GEMM (r11, for wo): 32x32 frags, depth-3 counted-vmcnt -------
template <int EPI>
__global__ __launch_bounds__(256) void k_gemm(const u16* __restrict__ A, const u16* __restrict__ Bt,
                                              int Kst, int klen, u16* __restrict__ Cb,
                                              float* __restrict__ Cf,
                                              const float* __restrict__ bias,
                                              const float* __restrict__ res,
                                              const float* __restrict__ mo, int goff,
                                              u16* __restrict__ vt) {
  const int tid = threadIdx.x;
  const int w = tid >> 6, lane = tid & 63;
  const int wr = w >> 1, wc = w & 1;
  const int l31 = lane & 31, hi = lane >> 5;

  const int nwg = gridDim.x * gridDim.y;
  const int id = blockIdx.y * gridDim.x + blockIdx.x;
  const int swz = (id & 7) * (nwg >> 3) + (id >> 3);
  const int tM = (swz / gridDim.x) * 128, tN = (swz % gridDim.x) * 128;
  const int N = gridDim.x * 128;
  const int koff = blockIdx.z * klen;

  __shared__ u16 lA[3][128 * 32];
  __shared__ u16 lB[3][128 * 32];
  f32x16 acc[2][2];
  #pragma unroll
  for (int m = 0; m < 2; ++m)
    #pragma unroll
    for (int n = 0; n < 2; ++n)
      #pragma unroll
      for (int r = 0; r < 16; ++r) acc[m][n][r] = 0.f;

  const int lrow = lane >> 2, lseg = lane & 3;
  const int fl = (lrow & 3) ^ ((lrow >> 2) & 3);
  const u16* gA = A + (size_t)(tM + w * 32 + lrow) * Kst + (lseg ^ fl) * 8 + koff;
  const u16* gB = Bt + (size_t)(tN + w * 32 + lrow) * Kst + (lseg ^ fl) * 8 + koff;
  const size_t rstep = (size_t)16 * Kst;
  const int wo0 = (w * 32) * 32, wo1 = (w * 32 + 16) * 32;
  const int fr = (l31 & 3) ^ ((l31 >> 2) & 3);
  const int c0 = (hi ^ fr) * 8;
  const int c1 = ((hi ^ fr) ^ 2) * 8;
  const int arow = (wr * 64 + l31) * 32;
  const int brow = (wc * 64 + l31) * 32;

#define STAGE(buf, ks)                        \
  do {                                        \
    gload16(gA + (ks), lA[buf] + wo0);        \
    gload16(gA + rstep + (ks), lA[buf] + wo1);\
    gload16(gB + (ks), lB[buf] + wo0);        \
    gload16(gB + rstep + (ks), lB[buf] + wo1);\
  } while (0)

#define COMPUTE(buf)                                                            \
  do {                                                                          \
    bf16x8 a00 = *(const bf16x8*)&lA[buf][arow + c0];                           \
    bf16x8 a01 = *(const bf16x8*)&lA[buf][arow + c1];                           \
    bf16x8 a10 = *(const bf16x8*)&lA[buf][arow + 1024 + c0];                    \
    bf16x8 a11 = *(const bf16x8*)&lA[buf][arow + 1024 + c1];                    \
    bf16x8 b00 = *(const bf16x8*)&lB[buf][brow + c0];                           \
    bf16x8 b01 = *(const bf16x8*)&lB[buf][brow + c1];                           \
    bf16x8 b10 = *(const bf16x8*)&lB[buf][brow + 1024 + c0];                    \
    bf16x8 b11 = *(const bf16x8*)&lB[buf][brow + 1024 + c1];                    \
    __builtin_amdgcn_s_setprio(1);                                              \
    acc[0][0] = MFMA32(a00, b00, acc[0][0]);                                    \
    acc[0][1] = MFMA32(a00, b10, acc[0][1]);                                    \
    acc[1][0] = MFMA32(a10, b00, acc[1][0]);                                    \
    acc[1][1] = MFMA32(a10, b10, acc[1][1]);                                    \
    acc[0][0] = MFMA32(a01, b01, acc[0][0]);                                    \
    acc[0][1] = MFMA32(a01, b11, acc[0][1]);                                    \
    acc[1][0] = MFMA32(a11, b01, acc[1][0]);                                    \
    acc[1][1] = MFMA32(a11, b11, acc[1][1]);                                    \
    __builtin_amdgcn_s_setprio(0);                                              \
  } while (0)

#define WAITBAR(Nst)                                          \
  do {                                                        \
    asm volatile("s_waitcnt vmcnt(" #Nst ")" ::: "memory");   \
    __builtin_amdgcn_s_barrier();                             \
    __builtin_amdgcn_sched_barrier(0);                        \
  } while (0)

  const int nt = klen >> 5;
  STAGE(0, 0);
  STAGE(1, 32);
  int ks = 64;
  for (int g = 0; g < nt / 3 - 1; ++g) {
    WAITBAR(4); STAGE(2, ks);      COMPUTE(0);
    WAITBAR(4); STAGE(0, ks + 32); COMPUTE(1);
    WAITBAR(4); STAGE(1, ks + 64); COMPUTE(2);
    ks += 96;
  }
  WAITBAR(4); STAGE(2, ks); COMPUTE(0);
  WAITBAR(4); COMPUTE(1);
  WAITBAR(0); COMPUTE(2);
#undef STAGE
#undef COMPUTE
#undef WAITBAR

  #pragma unroll
  for (int m = 0; m < 2; ++m)
    #pragma unroll
    for (int n = 0; n < 2; ++n) {
      int gcol = tN + wc * 64 + n * 32 + l31;
      #pragma unroll
      for (int q = 0; q < 4; ++q) {
        int grow0 = tM + wr * 64 + m * 32 + hi * 4 + q * 8;
        float g = mo[(size_t)(grow0 >> 10) * 6912 + goff + gcol];
        float bi = bias[gcol];
        #pragma unroll
        for (int r = 0; r < 4; ++r) {
          size_t idx = (size_t)(grow0 + r) * N + gcol;
          Cf[idx] = res[idx] + g * (acc[m][n][q * 4 + r] + bi);
        }
      }
    }
}

// ------- fc2 split-K x3 reduce (grid-stride, 4 float4/thread) -------
__global__ __launch_bounds__(256) void k_fc2red(const u16* __restrict__ p,
                                                const float* __restrict__ x1,
                                                const float* __restrict__ bias,
                                                const float* __restrict__ mo,
                                                float* __restrict__ out) {
  #pragma unroll
  for (int it = 0; it < 4; ++it) {
    size_t idx4 = (size_t)(blockIdx.x * 4 + it) * 256 + threadIdx.x;
    size_t i = idx4 * 4;  // over 8192*1152
    int row = (int)(i / 1152);
    int col = (int)(i - (size_t)row * 1152);
    int b = row >> 10;
    ushort4 a0 = *(const ushort4*)(p + i);
    ushort4 a1 = *(const ushort4*)(p + 9437184ull + i);
    ushort4 a2 = *(const ushort4*)(p + 18874368ull + i);
    float4 r = *(const float4*)(x1 + i);
    const float* gp = mo + (size_t)b * 6912 + 5760 + col;
    const float* bp = bias + col;
    float4 o;
    o.x = r.x + gp[0] * (bf2f(a0.x) + bf2f(a1.x) + bf2f(a2.x) + bp[0]);
    o.y = r.y + gp[1] * (bf2f(a0.y) + bf2f(a1.y) + bf2f(a2.y) + bp[1]);
    o.z = r.z + gp[2] * (bf2f(a0.z) + bf2f(a1.z) + bf2f(a2.z) + bp[2]);
    o.w = r.w + gp[3] * (bf2f(a0.w) + bf2f(a1.w) + bf2f(a2.w) + bp[3]);
    *(float4*)(out + i) = o;
  }
}

// ------- flash attention, swapped-QK^T, T14 async-STAGE split -------
__global__ __launch_bounds__(256) void k_attn(const u16* __restrict__ QKV, const u16* __restrict__ Vt,
                                              u16* __restrict__ O) {
  const int tid = threadIdx.x;
  const int w = tid >> 6, lane = tid & 63;
  const int lr = lane & 15, kg = lane >> 4;
  int bx = blockIdx.x;
  bx = (bx & 7) * 256 + (bx >> 3);
  const int qt = bx & 15, h = (bx >> 4) & 15, b = bx >> 8;

  __shared__ u16 lQ[64][104];
  __shared__ u16 lK[64][104];
  __shared__ u16 lVt[80][72];
  __shared__ u16 lPt[4][16][72];

  const size_t qkbase = (size_t)b * 1024 * 3456 + (size_t)h * 72;
  const u16* Qg = QKV + qkbase;
  const u16* Kg = QKV + qkbase + 1152;
  const u16* Vg = Vt + ((size_t)(b * 16 + h) * 72) * 1024;

  const uint4 z4 = make_uint4(0, 0, 0, 0);
  for (int L = tid; L < 192; L += 256) {
    int r = L / 3, s = L - (L / 3) * 3;
    *(uint4*)&lQ[r][72 + s * 8] = z4;
    *(uint4*)&lK[r][72 + s * 8] = z4;
  }
  for (int L = tid; L < 72; L += 256) {
    int r = L / 9, s = L - (L / 9) * 9;
    *(uint4*)&lVt[72 + r][s * 8] = z4;
  }
  {
    int L = tid; int r = L / 9, s = L - r * 9;
    *(uint4*)&lQ[r][s * 8] = *(const uint4*)(Qg + (size_t)(qt * 64 + r) * 3456 + s * 8);
    L = tid + 256; r = L / 9; s = L - r * 9;
    *(uint4*)&lQ[r][s * 8] = *(const uint4*)(Qg + (size_t)(qt * 64 + r) * 3456 + s * 8);
    if (tid < 64) {
      L = tid + 512; r = L / 9; s = L - r * 9;
      *(uint4*)&lQ[r][s * 8] = *(const uint4*)(Qg + (size_t)(qt * 64 + r) * 3456 + s * 8);
    }
  }

  // T14: per-thread staging indices (kt-independent), registers hold next tile
  const int kr0 = tid / 9, ks0 = tid - kr0 * 9;
  const int kr1 = (tid + 256) / 9, ks1 = (tid + 256) - kr1 * 9;
  const int kr2 = (tid + 512) / 9, ks2 = (tid + 512) - kr2 * 9;
  const int vd0 = tid >> 3, vd1 = (tid + 256) >> 3, vd2 = (tid + 512) >> 3, vsg = tid & 7;
  uint4 krg0, krg1, krg2, vrg0, vrg1, vrg2;

#define LOAD_TILE(KT)                                                              \
  do {                                                                            \
    krg0 = *(const uint4*)(Kg + (size_t)((KT) * 64 + kr0) * 3456 + ks0 * 8);       \
    krg1 = *(const uint4*)(Kg + (size_t)((KT) * 64 + kr1) * 3456 + ks1 * 8);       \
    vrg0 = *(const uint4*)(Vg + (size_t)vd0 * 1024 + (KT) * 64 + vsg * 8);         \
    vrg1 = *(const uint4*)(Vg + (size_t)vd1 * 1024 + (KT) * 64 + vsg * 8);         \
    if (tid < 64) {                                                               \
      krg2 = *(const uint4*)(Kg + (size_t)((KT) * 64 + kr2) * 3456 + ks2 * 8);     \
      vrg2 = *(const uint4*)(Vg + (size_t)vd2 * 1024 + (KT) * 64 + vsg * 8);       \
    }                                                                             \
  } while (0)

#define WRITE_TILE()                                                               \
  do {                                                                            \
    *(uint4*)&lK[kr0][ks0 * 8] = krg0;                                            \
    *(uint4*)&lK[kr1][ks1 * 8] = krg1;                                            \
    *(uint4*)&lVt[vd0][vsg * 8] = vrg0;                                           \
    *(uint4*)&lVt[vd1][vsg * 8] = vrg1;                                           \
    if (tid < 64) {                                                               \
      *(uint4*)&lK[kr2][ks2 * 8] = krg2;                                          \
      *(uint4*)&lVt[vd2][vsg * 8] = vrg2;                                         \
    }                                                                             \
  } while (0)

  LOAD_TILE(0);
  WRITE_TILE();
  __syncthreads();  // Q + tile 0 resident

  bf16x8 bq[3];
  #pragma unroll
  for (int ks = 0; ks < 3; ++ks) bq[ks] = *(const bf16x8*)&lQ[w * 16 + lr][ks * 32 + kg * 8];

  const float scale = 0.11785113019775793f;  // 1/sqrt(72)
  float mrun = -1e30f, lrun = 0.f;
  f32x4 oacc[5];
  #pragma unroll
  for (int nd = 0; nd < 5; ++nd) oacc[nd] = f32x4{0.f, 0.f, 0.f, 0.f};

  for (int kt = 0; kt < 16; ++kt) {
    if (kt < 15) LOAD_TILE(kt + 1);  // issue early: HBM latency hides under compute

    f32x4 sfr[4];
    __builtin_amdgcn_s_setprio(1);
    #pragma unroll
    for (int kb = 0; kb < 4; ++kb) {
      f32x4 sv = f32x4{0.f, 0.f, 0.f, 0.f};
      #pragma unroll
      for (int ks = 0; ks < 3; ++ks) {
        bf16x8 ak = *(const bf16x8*)&lK[kb * 16 + lr][ks * 32 + kg * 8];
        sv = MFMA16(ak, bq[ks], sv);
      }
      sfr[kb] = sv;
    }
    __builtin_amdgcn_s_setprio(0);

    float mx = sfr[0][0];
    #pragma unroll
    for (int kb = 0; kb < 4; ++kb)
      #pragma unroll
      for (int r = 0; r < 4; ++r) mx = fmaxf(mx, sfr[kb][r]);
    mx = fmaxf(mx, __shfl_xor(mx, 16));
    mx = fmaxf(mx, __shfl_xor(mx, 32));
    mx *= scale;
    float mn = fmaxf(mrun, mx);
    float al = __expf(mrun - mn);
    mrun = mn;
    float sum = 0.f;
    #pragma unroll
    for (int kb = 0; kb < 4; ++kb) {
      #pragma unroll
      for (int rp = 0; rp < 2; ++rp) {
        float p0 = __expf(__fmaf_rn(sfr[kb][2 * rp], scale, -mn));
        float p1 = __expf(__fmaf_rn(sfr[kb][2 * rp + 1], scale, -mn));
        sum += p0 + p1;
        u32 pk = (u32)f2bf(p0) | ((u32)f2bf(p1) << 16);
        *(u32*)&lPt[w][lr][kb * 16 + kg * 4 + rp * 2] = pk;
      }
    }
    sum += __shfl_xor(sum, 16);
    sum += __shfl_xor(sum, 32);
    lrun = lrun * al + sum;
    #pragma unroll
    for (int nd = 0; nd < 5; ++nd)
      #pragma unroll
      for (int r = 0; r < 4; ++r) oacc[nd][r] *= al;

    __builtin_amdgcn_s_setprio(1);
    #pragma unroll
    for (int s = 0; s < 2; ++s) {
      bf16x8 bp = *(const bf16x8*)&lPt[w][lr][s * 32 + kg * 8];
      #pragma unroll
      for (int nd = 0; nd < 5; ++nd) {
        bf16x8 av = *(const bf16x8*)&lVt[nd * 16 + lr][s * 32 + kg * 8];
        oacc[nd] = MFMA16(av, bp, oacc[nd]);
      }
    }
    __builtin_amdgcn_s_setprio(0);

    __syncthreads();  // all waves done reading tile kt from lK/lVt
    if (kt < 15) {
      WRITE_TILE();   // compiler waits the global loads' vmcnt here
      __syncthreads();  // tile kt+1 resident for all waves
    }
  }
#undef LOAD_TILE
#undef WRITE_TILE

  float inv = 1.f / lrun;
  size_t orow = ((size_t)b * 1024 + qt * 64 + w * 16 + lr) * 1152 + h * 72;
  #pragma unroll
  for (int nd = 0; nd < 5; ++nd) {
    int d0 = nd * 16 + kg * 4;
    if (d0 < 72) {
      ushort4 u;
      u.x = f2bf(oacc[nd][0] * inv);
      u.y = f2bf(oacc[nd][1] * inv);
      u.z = f2bf(oacc[nd][2] * inv);
      u.w = f2bf(oacc[nd][3] * inv);
      *(ushort4*)&O[orow + d0] = u;
    }
  }
}

extern "C" void kernel_launch(void* const* d_in, const int* in_sizes, int n_in,
                              void* d_out, int out_size, void* d_ws, size_t ws_size,
                              hipStream_t stream) {
  const float* x     = (const float*)d_in[0];
  const float* c     = (const float*)d_in[1];
  const float* ln1_w = (const float*)d_in[2];
  const float* ln1_b = (const float*)d_in[3];
  const float* wq    = (const float*)d_in[4];
  const float* wk    = (const float*)d_in[5];
  const float* wv    = (const float*)d_in[6];
  const float* wo    = (const float*)d_in[7];
  const float* wo_b  = (const float*)d_in[8];
  const float* ln2_w = (const float*)d_in[9];
  const float* ln2_b = (const float*)d_in[10];
  const float* fc1_w = (const float*)d_in[11];
  const float* fc1_b = (const float*)d_in[12];
  const float* fc2_w = (const float*)d_in[13];
  const float* fc2_b = (const float*)d_in[14];
  const float* ada_w = (const float*)d_in[15];
  const float* ada_b = (const float*)d_in[16];
  float* out = (float*)d_out;

  char* base = (char*)d_ws;
  size_t off = 0;
  auto alloc = [&](size_t nbytes) -> void* {
    void* p = base + off;
    off += (nbytes + 255) & ~(size_t)255;
    return p;
  };
  const size_t MD = 8192ull * 1152;
  float* partial = (float*)alloc(64ull * 6912 * 4);
  float* modb   = (float*)alloc(55296 * 4);
  u16* qkvT = (u16*)alloc(3584ull * 1152 * 2);   // padded to 3584 rows
  u16* woT  = (u16*)alloc(1152ull * 1152 * 2);
  u16* fc1T = (u16*)alloc(4608ull * 1152 * 2);
  u16* fc2T = (u16*)alloc(1280ull * 4608 * 2);   // padded to 1280 rows
  u16* hbuf = (u16*)alloc(MD * 2);               // h -> attnO -> h2
  float* x1 = (float*)alloc(MD * 4);
  u16* vtb  = (u16*)alloc(128ull * 72 * 1024 * 2);
  u16* fc2p = (u16*)alloc(3ull * MD * 2);        // bf16 partials x3, stride 1152
  u16* big  = (u16*)alloc(8192ull * 4608 * 2);   // qkv (stride 3456) then m1
  u16* qkv = big;
  u16* m1 = big;
  // total ws ~243 MB (fits 256 MiB = 268.4 MB)

  k_modproj1<<<dim3(27, 8), 256, 0, stream>>>(c, ada_w, partial);
  k_modproj2<<<27, 256, 0, stream>>>(partial, ada_b, modb);
  // batched: wq,wk,wv,wo in a single launch (z=0..3)
  k_tcvt4<<<dim3(36, 36, 4), 256, 0, stream>>>(
      wq, qkvT, wk, qkvT + 1152ull * 1152, wv, qkvT + 2304ull * 1152, wo, woT);
  k_tcvt<<<dim3(144, 36), 256, 0, stream>>>(fc1_w, fc1T, 1152, 4608);
  k_tcvt<<<dim3(36, 144), 256, 0, stream>>>(fc2_w, fc2T, 4608, 1152);

  // h = modulate(LN(x), sh_msa, sc_msa)
  k_lnmod<<<8192, 256, 0, stream>>>(x, ln1_w, ln1_b, modb, 0, 1152, hbuf);
  // qkv (4-phase): Q,K rows into qkv (stride 3456), V transposed into vtb
  k_gemm8p<3><<<dim3(14, 32), 512, 0, stream>>>(hbuf, qkvT, 1152, 1152, qkv, nullptr, vtb);
  // attention -> O (reuse hbuf)
  k_attn<<<2048, 256, 0, stream>>>(qkv, vtb, hbuf);
  // x1 = x + g_msa*(O@wo + wo_b)   (4-wave)
  k_gemm<1><<<dim3(9, 64), 256, 0, stream>>>(hbuf, woT, 1152, 1152, nullptr, x1, wo_b, x, modb, 2304, nullptr);
  // h2 = modulate(LN(x1), sh_mlp, sc_mlp)
  k_lnmod<<<8192, 256, 0, stream>>>(x1, ln2_w, ln2_b, modb, 3456, 4608, hbuf);
  // m1 = gelu(h2@fc1 + fc1_b)  (4-phase)
  k_gemm8p<2><<<dim3(18, 32), 512, 0, stream>>>(hbuf, fc1T, 1152, 1152, m1, fc1_b, nullptr);
  // fc2 split-K x3 (4-phase, klen=1536, 480 blocks) then fused reduce
  k_gemm8p<5><<<dim3(5, 32, 3), 512, 0, stream>>>(m1, fc2T, 4608, 1536, fc2p, nullptr, nullptr);
  k_fc2red<<<2304, 256, 0, stream>>>(fc2p, x1, fc2_b, modb, out);
}